// Round 7
// baseline (419.266 us; speedup 1.0000x reference)
//
#include <hip/hip_runtime.h>
#include <math.h>

// ---------------------------------------------------------------------------
// GCN encoder forward, bf16 MFMA formulation:
//   CSR build (hist->scan->fill) ; BN stats (fp32, partials + reduce)
//   xb16 = bn(x) in bf16 ; noise16 = bf16(noise) ; Wt = W^T in bf16
//   hs16 = (concat srcs @ W) * dinv[row]   (MFMA gemm, bf16 out)
//   out[d] = act(dinv[d]*(sum_in hs16[src] + hs16[d]) + bias)
// A/hs buffers row-padded to NPAD (=ceil(N/128)*128): GEMM has no boundary
// conditionals; pad rows produce garbage that is never gathered (dead).
// GEMM: all 8 A-frags issued up front per source + W double-buffered in regs.
// ---------------------------------------------------------------------------

typedef short bf16x8 __attribute__((ext_vector_type(8)));
typedef float f32x4 __attribute__((ext_vector_type(4)));

#define BN_G 1024

__device__ inline unsigned short f2bf(float f) {  // RNE
    unsigned int u = __builtin_bit_cast(unsigned int, f);
    u += 0x7fff + ((u >> 16) & 1);
    return (unsigned short)(u >> 16);
}
__device__ inline float bfl(unsigned int u) { return __builtin_bit_cast(float, u << 16); }
__device__ inline float bfh(unsigned int u) { return __builtin_bit_cast(float, u & 0xffff0000u); }
__device__ inline unsigned int pack2(float lo, float hi) {
    return ((unsigned int)f2bf(hi) << 16) | f2bf(lo);
}
__device__ inline void acc8(float* a, uint4 v) {
    a[0] += bfl(v.x); a[1] += bfh(v.x);
    a[2] += bfl(v.y); a[3] += bfh(v.y);
    a[4] += bfl(v.z); a[5] += bfh(v.z);
    a[6] += bfl(v.w); a[7] += bfh(v.w);
}

__global__ void zero_i32(int* __restrict__ p, int n) {
    int i = blockIdx.x * blockDim.x + threadIdx.x;
    if (i < n) p[i] = 0;
}

__global__ void count_deg(const int* __restrict__ ei, int* __restrict__ cnt, int E) {
    int e = blockIdx.x * blockDim.x + threadIdx.x;
    if (e < E) atomicAdd(&cnt[ei[E + e]], 1);
}

__global__ void dinv_from_cnt(const int* __restrict__ cnt, float* __restrict__ dinv, int n) {
    int i = blockIdx.x * blockDim.x + threadIdx.x;
    if (i < n) dinv[i] = rsqrtf((float)cnt[i] + 1.0f);   // +1 self-loop
}

#define SCAN_BLK 256
#define SCAN_ELEMS 1024

__global__ void scan_blocks(const int* __restrict__ cnt, int* __restrict__ out,
                            int* __restrict__ bsums, int n) {
    __shared__ int lds[SCAN_BLK];
    int base = blockIdx.x * SCAN_ELEMS;
    int t = threadIdx.x;
    int v[4];
    int s = 0;
#pragma unroll
    for (int j = 0; j < 4; j++) {
        int i = base + t * 4 + j;
        v[j] = s;
        s += (i < n) ? cnt[i] : 0;
    }
    lds[t] = s;
    __syncthreads();
    for (int off = 1; off < SCAN_BLK; off <<= 1) {
        int val = (t >= off) ? lds[t - off] : 0;
        __syncthreads();
        lds[t] += val;
        __syncthreads();
    }
    int excl = (t == 0) ? 0 : lds[t - 1];
#pragma unroll
    for (int j = 0; j < 4; j++) {
        int i = base + t * 4 + j;
        if (i < n) out[i] = excl + v[j];
    }
    if (t == SCAN_BLK - 1) bsums[blockIdx.x] = lds[t];
}

__global__ void scan_bsums(int* __restrict__ bsums, int nb) {
    if (threadIdx.x == 0 && blockIdx.x == 0) {
        int acc = 0;
        for (int i = 0; i < nb; i++) { int c = bsums[i]; bsums[i] = acc; acc += c; }
    }
}

__global__ void scan_add(int* __restrict__ row_ptr, const int* __restrict__ bsums, int n, int E) {
    int i = blockIdx.x * blockDim.x + threadIdx.x;
    if (i < n) row_ptr[i] += bsums[i / SCAN_ELEMS];
    if (i == 0) row_ptr[n] = E;
}

__global__ void fill_edges(const int* __restrict__ ei, const int* __restrict__ row_ptr,
                           int* __restrict__ cnt, int* __restrict__ edge_src, int E) {
    int e = blockIdx.x * blockDim.x + threadIdx.x;
    if (e >= E) return;
    int s = ei[e], d = ei[E + e];
    int off = atomicSub(&cnt[d], 1) - 1;
    edge_src[row_ptr[d] + off] = s;
}

// ---- BN statistics: 4-deep row unroll, non-atomic partials ----------------
__global__ __launch_bounds__(256) void bn_stats(const float4* __restrict__ x4,
                                                float* __restrict__ partials, int n) {
    int t = threadIdx.x;
    int cg = t & 31;          // column group (float4)
    int rs = t >> 5;          // row slice 0..7, 4 rows each
    float4 s = make_float4(0.f, 0.f, 0.f, 0.f);
    float4 q = make_float4(0.f, 0.f, 0.f, 0.f);
    const float4 z4 = make_float4(0.f, 0.f, 0.f, 0.f);
    const int stride = BN_G * 32;
    for (int r0 = blockIdx.x * 32 + rs * 4; r0 < n; r0 += stride) {
        float4 v0 = x4[(size_t)r0 * 32 + cg];
        float4 v1 = (r0 + 1 < n) ? x4[(size_t)(r0 + 1) * 32 + cg] : z4;
        float4 v2 = (r0 + 2 < n) ? x4[(size_t)(r0 + 2) * 32 + cg] : z4;
        float4 v3 = (r0 + 3 < n) ? x4[(size_t)(r0 + 3) * 32 + cg] : z4;
        s.x += v0.x + v1.x + v2.x + v3.x;
        s.y += v0.y + v1.y + v2.y + v3.y;
        s.z += v0.z + v1.z + v2.z + v3.z;
        s.w += v0.w + v1.w + v2.w + v3.w;
        q.x = fmaf(v0.x, v0.x, fmaf(v1.x, v1.x, fmaf(v2.x, v2.x, fmaf(v3.x, v3.x, q.x))));
        q.y = fmaf(v0.y, v0.y, fmaf(v1.y, v1.y, fmaf(v2.y, v2.y, fmaf(v3.y, v3.y, q.y))));
        q.z = fmaf(v0.z, v0.z, fmaf(v1.z, v1.z, fmaf(v2.z, v2.z, fmaf(v3.z, v3.z, q.z))));
        q.w = fmaf(v0.w, v0.w, fmaf(v1.w, v1.w, fmaf(v2.w, v2.w, fmaf(v3.w, v3.w, q.w))));
    }
    __shared__ float4 lds[2][8][32];
    lds[0][rs][cg] = s;
    lds[1][rs][cg] = q;
    __syncthreads();
    if (t < 64) {
        int which = t >> 5;   // 0: sum, 1: sumsq
        int c = t & 31;
        float4 a = lds[which][0][c];
#pragma unroll
        for (int i = 1; i < 8; i++) {
            float4 b = lds[which][i][c];
            a.x += b.x; a.y += b.y; a.z += b.z; a.w += b.w;
        }
        int base = which * 128 + c * 4;
        partials[(size_t)(base + 0) * BN_G + blockIdx.x] = a.x;
        partials[(size_t)(base + 1) * BN_G + blockIdx.x] = a.y;
        partials[(size_t)(base + 2) * BN_G + blockIdx.x] = a.z;
        partials[(size_t)(base + 3) * BN_G + blockIdx.x] = a.w;
    }
}

// one block per output element c in [0,256): stats[c] = sum over BN_G partials
__global__ void bn_reduce(const float4* __restrict__ partials4, float* __restrict__ stats) {
    __shared__ float red[256];
    int c = blockIdx.x, t = threadIdx.x;
    float4 v = partials4[(size_t)c * (BN_G / 4) + t];
    red[t] = v.x + v.y + v.z + v.w;
    __syncthreads();
    for (int off = 128; off > 0; off >>= 1) {
        if (t < off) red[t] += red[t + off];
        __syncthreads();
    }
    if (t == 0) stats[c] = red[0];
}

__global__ void bn_finalize(const float* __restrict__ colsum, const float* __restrict__ colsumsq,
                            const float* __restrict__ gamma, const float* __restrict__ beta,
                            float* __restrict__ scale, float* __restrict__ shift, float invN) {
    int c = threadIdx.x;
    float mu = colsum[c] * invN;
    float var = colsumsq[c] * invN - mu * mu;
    float sc = gamma[c] / sqrtf(var + 1e-5f);
    scale[c] = sc;
    shift[c] = beta[c] - mu * sc;
}

// x -> bn -> bf16 ; noise -> bf16. One pass, float4 in / ushort4 out.
__global__ void convert_inputs(const float4* __restrict__ x4, const float4* __restrict__ n4,
                               const float* __restrict__ scale, const float* __restrict__ shift,
                               ushort4* __restrict__ xb, ushort4* __restrict__ nb, int total4) {
    int i = blockIdx.x * blockDim.x + threadIdx.x;
    if (i >= total4) return;
    int c4 = (i & 31) << 2;
    float4 sc = *reinterpret_cast<const float4*>(scale + c4);
    float4 sh = *reinterpret_cast<const float4*>(shift + c4);
    float4 v = x4[i];
    ushort4 o;
    o.x = f2bf(fmaf(v.x, sc.x, sh.x));
    o.y = f2bf(fmaf(v.y, sc.y, sh.y));
    o.z = f2bf(fmaf(v.z, sc.z, sh.z));
    o.w = f2bf(fmaf(v.w, sc.w, sh.w));
    xb[i] = o;
    float4 w = n4[i];
    ushort4 p;
    p.x = f2bf(w.x); p.y = f2bf(w.y); p.z = f2bf(w.z); p.w = f2bf(w.w);
    nb[i] = p;
}

// Wt[c][k] = bf16(W[k][c]); Wt row stride = K
__global__ void transpose_w(const float* __restrict__ W, unsigned short* __restrict__ Wt,
                            int K, int C) {
    int i = blockIdx.x * blockDim.x + threadIdx.x;
    if (i >= K * C) return;
    int k = i / C, c = i % C;
    Wt[(size_t)c * K + k] = f2bf(W[i]);
}

// ---------------------------------------------------------------------------
// MFMA GEMM: hs[MP x 128] = (sum_s A_s[MP x 128] @ W[s*128:, :]) * dinv[row]
// MP is a multiple of 64 (row-padded buffers; no boundary checks).
// Block 64 rows x 128 cols, 4 waves 2x2; wave tile 32 rows x 64 cols.
// Per source: all 8 A-frags issued up front; W frags double-buffered per kc.
// ---------------------------------------------------------------------------
template <int NSRC>
__global__ __launch_bounds__(256, 4) void gemm_mfma(
    const unsigned short* __restrict__ A0, const unsigned short* __restrict__ A1,
    const unsigned short* __restrict__ A2,
    const unsigned short* __restrict__ Wt,   // [128 cols][NSRC*128 k]
    const float* __restrict__ dinv, unsigned short* __restrict__ out)
{
    constexpr int KTOT = NSRC * 128;
    const int lane = threadIdx.x & 63;
    const int wid  = threadIdx.x >> 6;
    const int wr   = wid >> 1, wc = wid & 1;
    const int l15  = lane & 15, lhi = lane >> 4;
    const int c0   = wc * 64;
    const long r0 = (long)blockIdx.x * 64 + wr * 32 + l15;
    const long r1 = r0 + 16;

    f32x4 acc[2][4];
#pragma unroll
    for (int g = 0; g < 2; g++)
#pragma unroll
        for (int n = 0; n < 4; n++)
            acc[g][n] = (f32x4){0.f, 0.f, 0.f, 0.f};

    const unsigned short* __restrict__ srcs[3] = {A0, A1, A2};
#pragma unroll
    for (int s = 0; s < NSRC; s++) {
        const unsigned short* __restrict__ A = srcs[s];
        const unsigned short* a0p = A + r0 * 128 + lhi * 8;
        const unsigned short* a1p = A + r1 * 128 + lhi * 8;
        // issue all 8 A-fragment loads up front (8 KB/wave in flight)
        bf16x8 af0[4], af1[4];
#pragma unroll
        for (int kc = 0; kc < 4; kc++) {
            af0[kc] = *reinterpret_cast<const bf16x8*>(a0p + kc * 32);
            af1[kc] = *reinterpret_cast<const bf16x8*>(a1p + kc * 32);
        }
        const unsigned short* wp = Wt + (size_t)(c0 + l15) * KTOT + s * 128 + lhi * 8;
        bf16x8 w[4], wn[4];
#pragma unroll
        for (int n = 0; n < 4; n++)
            w[n] = *reinterpret_cast<const bf16x8*>(wp + (size_t)(n * 16) * KTOT);
#pragma unroll
        for (int kc = 0; kc < 4; kc++) {
            if (kc < 3) {
#pragma unroll
                for (int n = 0; n < 4; n++)
                    wn[n] = *reinterpret_cast<const bf16x8*>(wp + (kc + 1) * 32 +
                                                             (size_t)(n * 16) * KTOT);
            }
#pragma unroll
            for (int n = 0; n < 4; n++) {
                acc[0][n] = __builtin_amdgcn_mfma_f32_16x16x32_bf16(w[n], af0[kc], acc[0][n], 0, 0, 0);
                acc[1][n] = __builtin_amdgcn_mfma_f32_16x16x32_bf16(w[n], af1[kc], acc[1][n], 0, 0, 0);
            }
            if (kc < 3) {
#pragma unroll
                for (int n = 0; n < 4; n++) w[n] = wn[n];
            }
        }
    }

#pragma unroll
    for (int g = 0; g < 2; g++) {
        long row = g ? r1 : r0;
        float dv = dinv[row];
        unsigned short* op = out + row * 128 + c0 + lhi * 4;
#pragma unroll
        for (int n = 0; n < 4; n++) {
            f32x4 v = acc[g][n];
            ushort4 pk;
            pk.x = f2bf(v[0] * dv);
            pk.y = f2bf(v[1] * dv);
            pk.z = f2bf(v[2] * dv);
            pk.w = f2bf(v[3] * dv);
            *reinterpret_cast<ushort4*>(op + n * 16) = pk;
        }
    }
}

// ---------------------------------------------------------------------------
// CSR gather: one wave per node; 16 lanes x uint4 (16B) cover one 256B row;
// 4 sub-groups stride the edge list; cross-sub shuffle reduce at the end.
// ---------------------------------------------------------------------------
template <bool RELU>
__global__ void gather16(const uint4* __restrict__ hs4, const float* __restrict__ dinv,
                         const int* __restrict__ row_ptr, const int* __restrict__ edge_src,
                         const float* __restrict__ bias, uint4* __restrict__ out4, int n) {
    int node = blockIdx.x * 4 + (threadIdx.x >> 6);
    if (node >= n) return;
    int lane = threadIdx.x & 63;
    int cl = lane & 15, sub = lane >> 4;
    int beg = row_ptr[node], end = row_ptr[node + 1];
    float a0[8] = {0.f,0.f,0.f,0.f,0.f,0.f,0.f,0.f};
    float a1[8] = {0.f,0.f,0.f,0.f,0.f,0.f,0.f,0.f};
    if (sub == 0) acc8(a0, hs4[(size_t)node * 16 + cl]);   // self-loop
    int e = beg + sub;
    for (; e + 4 < end; e += 8) {
        uint4 v0 = hs4[(size_t)edge_src[e] * 16 + cl];
        uint4 v1 = hs4[(size_t)edge_src[e + 4] * 16 + cl];
        acc8(a0, v0);
        acc8(a1, v1);
    }
    if (e < end) acc8(a0, hs4[(size_t)edge_src[e] * 16 + cl]);
#pragma unroll
    for (int i = 0; i < 8; i++) a0[i] += a1[i];
#pragma unroll
    for (int i = 0; i < 8; i++) {
        a0[i] += __shfl_xor(a0[i], 16);
        a0[i] += __shfl_xor(a0[i], 32);
    }
    if (sub == 0) {
        float dv = dinv[node];
        float4 b0 = *reinterpret_cast<const float4*>(bias + cl * 8);
        float4 b1 = *reinterpret_cast<const float4*>(bias + cl * 8 + 4);
        float r0 = fmaf(a0[0], dv, b0.x), r1 = fmaf(a0[1], dv, b0.y);
        float r2 = fmaf(a0[2], dv, b0.z), r3 = fmaf(a0[3], dv, b0.w);
        float r4 = fmaf(a0[4], dv, b1.x), r5 = fmaf(a0[5], dv, b1.y);
        float r6 = fmaf(a0[6], dv, b1.z), r7 = fmaf(a0[7], dv, b1.w);
        if (RELU) {
            r0 = fmaxf(r0, 0.f); r1 = fmaxf(r1, 0.f); r2 = fmaxf(r2, 0.f); r3 = fmaxf(r3, 0.f);
            r4 = fmaxf(r4, 0.f); r5 = fmaxf(r5, 0.f); r6 = fmaxf(r6, 0.f); r7 = fmaxf(r7, 0.f);
        }
        uint4 o;
        o.x = pack2(r0, r1); o.y = pack2(r2, r3);
        o.z = pack2(r4, r5); o.w = pack2(r6, r7);
        out4[(size_t)node * 16 + cl] = o;
    }
}

// final: t rows = [tm(64) | ts(64)] bf16 -> zm, zs fp32
__global__ void gather_dual(const uint4* __restrict__ hs4, const float* __restrict__ dinv,
                            const int* __restrict__ row_ptr, const int* __restrict__ edge_src,
                            const float* __restrict__ bm, const float* __restrict__ bs,
                            float* __restrict__ zm, float* __restrict__ zs, int n) {
    int node = blockIdx.x * 4 + (threadIdx.x >> 6);
    if (node >= n) return;
    int lane = threadIdx.x & 63;
    int cl = lane & 15, sub = lane >> 4;
    int beg = row_ptr[node], end = row_ptr[node + 1];
    float a0[8] = {0.f,0.f,0.f,0.f,0.f,0.f,0.f,0.f};
    float a1[8] = {0.f,0.f,0.f,0.f,0.f,0.f,0.f,0.f};
    if (sub == 0) acc8(a0, hs4[(size_t)node * 16 + cl]);
    int e = beg + sub;
    for (; e + 4 < end; e += 8) {
        uint4 v0 = hs4[(size_t)edge_src[e] * 16 + cl];
        uint4 v1 = hs4[(size_t)edge_src[e + 4] * 16 + cl];
        acc8(a0, v0);
        acc8(a1, v1);
    }
    if (e < end) acc8(a0, hs4[(size_t)edge_src[e] * 16 + cl]);
#pragma unroll
    for (int i = 0; i < 8; i++) a0[i] += a1[i];
#pragma unroll
    for (int i = 0; i < 8; i++) {
        a0[i] += __shfl_xor(a0[i], 16);
        a0[i] += __shfl_xor(a0[i], 32);
    }
    if (sub == 0) {
        float dv = dinv[node];
        const float* bp = (cl < 8) ? (bm + cl * 8) : (bs + (cl - 8) * 8);
        float* zp = (cl < 8) ? (zm + (size_t)node * 64 + cl * 8)
                             : (zs + (size_t)node * 64 + (cl - 8) * 8);
        float4 b0 = *reinterpret_cast<const float4*>(bp);
        float4 b1 = *reinterpret_cast<const float4*>(bp + 4);
        float4 o0 = make_float4(fmaf(a0[0], dv, b0.x), fmaf(a0[1], dv, b0.y),
                                fmaf(a0[2], dv, b0.z), fmaf(a0[3], dv, b0.w));
        float4 o1 = make_float4(fmaf(a0[4], dv, b1.x), fmaf(a0[5], dv, b1.y),
                                fmaf(a0[6], dv, b1.z), fmaf(a0[7], dv, b1.w));
        *reinterpret_cast<float4*>(zp) = o0;
        *reinterpret_cast<float4*>(zp + 4) = o1;
    }
}

// ---------------------------------------------------------------------------

extern "C" void kernel_launch(void* const* d_in, const int* in_sizes, int n_in,
                              void* d_out, int out_size, void* d_ws, size_t ws_size,
                              hipStream_t stream) {
    const float* x     = (const float*)d_in[0];
    const float* noise = (const float*)d_in[1];
    const int*   ei    = (const int*)d_in[2];
    const float* gamma = (const float*)d_in[3];
    const float* beta  = (const float*)d_in[4];
    const float* W1    = (const float*)d_in[5];
    const float* b1    = (const float*)d_in[6];
    const float* W2    = (const float*)d_in[7];
    const float* b2    = (const float*)d_in[8];
    const float* Wm    = (const float*)d_in[9];
    const float* bm    = (const float*)d_in[10];
    const float* Ws    = (const float*)d_in[11];
    const float* bs    = (const float*)d_in[12];

    const int N  = in_sizes[0] / 128;
    const int E  = in_sizes[2] / 2;
    const int NPAD = (N + 127) & ~127;        // row-padded size for GEMM buffers
    const int nb = (N + SCAN_ELEMS - 1) / SCAN_ELEMS;

    auto align256 = [](size_t b) { return (b + 255) & ~(size_t)255; };
    char* p = (char*)d_ws;
    int* cnt      = (int*)p;  p += align256((size_t)N * 4);
    int* row_ptr  = (int*)p;  p += align256((size_t)(N + 1) * 4);
    int* edge_src = (int*)p;  p += align256((size_t)E * 4);
    int* bsums    = (int*)p;  p += align256((size_t)nb * 4);
    float* dinv   = (float*)p; p += align256((size_t)NPAD * 4);
    float* stats  = (float*)p; p += align256(512 * 4);
    float* bnpart = (float*)p; p += align256((size_t)256 * BN_G * 4);
    unsigned short* Wt1 = (unsigned short*)p; p += align256(128 * 128 * 2);
    unsigned short* Wt2 = (unsigned short*)p; p += align256(128 * 384 * 2);
    unsigned short* Wtc = (unsigned short*)p; p += align256(128 * 256 * 2);
    unsigned short* xb16 = (unsigned short*)p; p += align256((size_t)NPAD * 128 * 2);
    unsigned short* n16  = (unsigned short*)p; p += align256((size_t)NPAD * 128 * 2);  // noise, then hs3
    unsigned short* h16  = (unsigned short*)p; p += align256((size_t)NPAD * 128 * 2);  // h1, then h2

    float* colsum   = stats;
    float* colsumsq = stats + 128;
    float* scale    = stats + 256;
    float* shift    = stats + 384;

    float* dout = (float*)d_out;                       // N*128 fp32
    unsigned short* hs12 = (unsigned short*)d_out;     // conv1/2 hs scratch (bf16, NPAD rows fit)
    unsigned short* hs3  = n16;                        // noise dead after conv2
    float* zm = dout;                                  // [N*64]
    float* zs = dout + (size_t)N * 64;                 // [N*64]

    const int gblocks = NPAD / 64;
    const int nblocks4 = (N + 3) / 4;

    // --- graph structure + BN stats + conversions ---
    zero_i32<<<(N + 255) / 256, 256, 0, stream>>>(cnt, N);
    count_deg<<<(E + 255) / 256, 256, 0, stream>>>(ei, cnt, E);
    bn_stats<<<BN_G, 256, 0, stream>>>((const float4*)x, bnpart, N);
    bn_reduce<<<256, 256, 0, stream>>>((const float4*)bnpart, stats);
    bn_finalize<<<1, 128, 0, stream>>>(colsum, colsumsq, gamma, beta, scale, shift, 1.0f / (float)N);
    scan_blocks<<<nb, SCAN_BLK, 0, stream>>>(cnt, row_ptr, bsums, N);
    scan_bsums<<<1, 64, 0, stream>>>(bsums, nb);
    scan_add<<<(N + 255) / 256, 256, 0, stream>>>(row_ptr, bsums, N, E);
    dinv_from_cnt<<<(N + 255) / 256, 256, 0, stream>>>(cnt, dinv, N);
    fill_edges<<<(E + 255) / 256, 256, 0, stream>>>(ei, row_ptr, cnt, edge_src, E);
    convert_inputs<<<(N * 32 + 255) / 256, 256, 0, stream>>>(
        (const float4*)x, (const float4*)noise, scale, shift,
        (ushort4*)xb16, (ushort4*)n16, N * 32);
    transpose_w<<<(128 * 128 + 255) / 256, 256, 0, stream>>>(W1, Wt1, 128, 128);
    transpose_w<<<(384 * 128 + 255) / 256, 256, 0, stream>>>(W2, Wt2, 384, 128);
    transpose_w<<<(256 * 64 + 255) / 256, 256, 0, stream>>>(Wm, Wtc, 256, 64);
    transpose_w<<<(256 * 64 + 255) / 256, 256, 0, stream>>>(Ws, Wtc + 64 * 256, 256, 64);

    // conv1
    gemm_mfma<1><<<gblocks, 256, 0, stream>>>(xb16, nullptr, nullptr, Wt1, dinv, hs12);
    gather16<true><<<nblocks4, 256, 0, stream>>>((const uint4*)hs12, dinv, row_ptr,
                                                 edge_src, b1, (uint4*)h16, N);
    // conv2
    gemm_mfma<3><<<gblocks, 256, 0, stream>>>(xb16, n16, h16, Wt2, dinv, hs12);
    gather16<true><<<nblocks4, 256, 0, stream>>>((const uint4*)hs12, dinv, row_ptr,
                                                 edge_src, b2, (uint4*)h16, N);
    // mean/logstd fused (hs -> n16 slot; d_out now gets final fp32 outputs)
    gemm_mfma<2><<<gblocks, 256, 0, stream>>>(xb16, h16, nullptr, Wtc, dinv, hs3);
    gather_dual<<<nblocks4, 256, 0, stream>>>((const uint4*)hs3, dinv, row_ptr,
                                              edge_src, bm, bs, zm, zs, N);
}

// Round 8
// 405.120 us; speedup vs baseline: 1.0349x; 1.0349x over previous
//
#include <hip/hip_runtime.h>
#include <math.h>

// ---------------------------------------------------------------------------
// GCN encoder forward, bf16 MFMA formulation:
//   CSR build (hist->scan->fill) ; BN stats (fp32, partials + reduce)
//   xb16 = bn(x) in bf16 ; noise16 = bf16(noise) ; Wt = W^T in bf16
//   hs16 = (concat srcs @ W) * dinv[row]   (MFMA gemm, bf16 out)
//   out[d] = act(dinv[d]*(sum_in hs16[src] + hs16[d]) + bias)
// GEMM: A staged to LDS via global_load_lds (async DMA, dbuf across sources),
// XOR-swizzled granules (linear dest + pre-swizzled source + swizzled read).
// ---------------------------------------------------------------------------

typedef short bf16x8 __attribute__((ext_vector_type(8)));
typedef float f32x4 __attribute__((ext_vector_type(4)));

#define BN_G 1024

__device__ inline unsigned short f2bf(float f) {  // RNE
    unsigned int u = __builtin_bit_cast(unsigned int, f);
    u += 0x7fff + ((u >> 16) & 1);
    return (unsigned short)(u >> 16);
}
__device__ inline float bfl(unsigned int u) { return __builtin_bit_cast(float, u << 16); }
__device__ inline float bfh(unsigned int u) { return __builtin_bit_cast(float, u & 0xffff0000u); }
__device__ inline unsigned int pack2(float lo, float hi) {
    return ((unsigned int)f2bf(hi) << 16) | f2bf(lo);
}
__device__ inline void acc8(float* a, uint4 v) {
    a[0] += bfl(v.x); a[1] += bfh(v.x);
    a[2] += bfl(v.y); a[3] += bfh(v.y);
    a[4] += bfl(v.z); a[5] += bfh(v.z);
    a[6] += bfl(v.w); a[7] += bfh(v.w);
}

__device__ __forceinline__ void gload_lds16(const void* g, void* l) {
    __builtin_amdgcn_global_load_lds(
        (const __attribute__((address_space(1))) unsigned int*)g,
        (__attribute__((address_space(3))) unsigned int*)l, 16, 0, 0);
}

__global__ void zero_i32(int* __restrict__ p, int n) {
    int i = blockIdx.x * blockDim.x + threadIdx.x;
    if (i < n) p[i] = 0;
}

__global__ void count_deg(const int* __restrict__ ei, int* __restrict__ cnt, int E) {
    int e = blockIdx.x * blockDim.x + threadIdx.x;
    if (e < E) atomicAdd(&cnt[ei[E + e]], 1);
}

__global__ void dinv_from_cnt(const int* __restrict__ cnt, float* __restrict__ dinv, int n) {
    int i = blockIdx.x * blockDim.x + threadIdx.x;
    if (i < n) dinv[i] = rsqrtf((float)cnt[i] + 1.0f);   // +1 self-loop
}

#define SCAN_BLK 256
#define SCAN_ELEMS 1024

__global__ void scan_blocks(const int* __restrict__ cnt, int* __restrict__ out,
                            int* __restrict__ bsums, int n) {
    __shared__ int lds[SCAN_BLK];
    int base = blockIdx.x * SCAN_ELEMS;
    int t = threadIdx.x;
    int v[4];
    int s = 0;
#pragma unroll
    for (int j = 0; j < 4; j++) {
        int i = base + t * 4 + j;
        v[j] = s;
        s += (i < n) ? cnt[i] : 0;
    }
    lds[t] = s;
    __syncthreads();
    for (int off = 1; off < SCAN_BLK; off <<= 1) {
        int val = (t >= off) ? lds[t - off] : 0;
        __syncthreads();
        lds[t] += val;
        __syncthreads();
    }
    int excl = (t == 0) ? 0 : lds[t - 1];
#pragma unroll
    for (int j = 0; j < 4; j++) {
        int i = base + t * 4 + j;
        if (i < n) out[i] = excl + v[j];
    }
    if (t == SCAN_BLK - 1) bsums[blockIdx.x] = lds[t];
}

__global__ void scan_bsums(int* __restrict__ bsums, int nb) {
    if (threadIdx.x == 0 && blockIdx.x == 0) {
        int acc = 0;
        for (int i = 0; i < nb; i++) { int c = bsums[i]; bsums[i] = acc; acc += c; }
    }
}

__global__ void scan_add(int* __restrict__ row_ptr, const int* __restrict__ bsums, int n, int E) {
    int i = blockIdx.x * blockDim.x + threadIdx.x;
    if (i < n) row_ptr[i] += bsums[i / SCAN_ELEMS];
    if (i == 0) row_ptr[n] = E;
}

__global__ void fill_edges(const int* __restrict__ ei, const int* __restrict__ row_ptr,
                           int* __restrict__ cnt, int* __restrict__ edge_src, int E) {
    int e = blockIdx.x * blockDim.x + threadIdx.x;
    if (e >= E) return;
    int s = ei[e], d = ei[E + e];
    int off = atomicSub(&cnt[d], 1) - 1;
    edge_src[row_ptr[d] + off] = s;
}

// ---- BN statistics: 4-deep row unroll, non-atomic partials ----------------
__global__ __launch_bounds__(256) void bn_stats(const float4* __restrict__ x4,
                                                float* __restrict__ partials, int n) {
    int t = threadIdx.x;
    int cg = t & 31;          // column group (float4)
    int rs = t >> 5;          // row slice 0..7, 4 rows each
    float4 s = make_float4(0.f, 0.f, 0.f, 0.f);
    float4 q = make_float4(0.f, 0.f, 0.f, 0.f);
    const float4 z4 = make_float4(0.f, 0.f, 0.f, 0.f);
    const int stride = BN_G * 32;
    for (int r0 = blockIdx.x * 32 + rs * 4; r0 < n; r0 += stride) {
        float4 v0 = x4[(size_t)r0 * 32 + cg];
        float4 v1 = (r0 + 1 < n) ? x4[(size_t)(r0 + 1) * 32 + cg] : z4;
        float4 v2 = (r0 + 2 < n) ? x4[(size_t)(r0 + 2) * 32 + cg] : z4;
        float4 v3 = (r0 + 3 < n) ? x4[(size_t)(r0 + 3) * 32 + cg] : z4;
        s.x += v0.x + v1.x + v2.x + v3.x;
        s.y += v0.y + v1.y + v2.y + v3.y;
        s.z += v0.z + v1.z + v2.z + v3.z;
        s.w += v0.w + v1.w + v2.w + v3.w;
        q.x = fmaf(v0.x, v0.x, fmaf(v1.x, v1.x, fmaf(v2.x, v2.x, fmaf(v3.x, v3.x, q.x))));
        q.y = fmaf(v0.y, v0.y, fmaf(v1.y, v1.y, fmaf(v2.y, v2.y, fmaf(v3.y, v3.y, q.y))));
        q.z = fmaf(v0.z, v0.z, fmaf(v1.z, v1.z, fmaf(v2.z, v2.z, fmaf(v3.z, v3.z, q.z))));
        q.w = fmaf(v0.w, v0.w, fmaf(v1.w, v1.w, fmaf(v2.w, v2.w, fmaf(v3.w, v3.w, q.w))));
    }
    __shared__ float4 lds[2][8][32];
    lds[0][rs][cg] = s;
    lds[1][rs][cg] = q;
    __syncthreads();
    if (t < 64) {
        int which = t >> 5;   // 0: sum, 1: sumsq
        int c = t & 31;
        float4 a = lds[which][0][c];
#pragma unroll
        for (int i = 1; i < 8; i++) {
            float4 b = lds[which][i][c];
            a.x += b.x; a.y += b.y; a.z += b.z; a.w += b.w;
        }
        int base = which * 128 + c * 4;
        partials[(size_t)(base + 0) * BN_G + blockIdx.x] = a.x;
        partials[(size_t)(base + 1) * BN_G + blockIdx.x] = a.y;
        partials[(size_t)(base + 2) * BN_G + blockIdx.x] = a.z;
        partials[(size_t)(base + 3) * BN_G + blockIdx.x] = a.w;
    }
}

// one block per output element c in [0,256): stats[c] = sum over BN_G partials
__global__ void bn_reduce(const float4* __restrict__ partials4, float* __restrict__ stats) {
    __shared__ float red[256];
    int c = blockIdx.x, t = threadIdx.x;
    float4 v = partials4[(size_t)c * (BN_G / 4) + t];
    red[t] = v.x + v.y + v.z + v.w;
    __syncthreads();
    for (int off = 128; off > 0; off >>= 1) {
        if (t < off) red[t] += red[t + off];
        __syncthreads();
    }
    if (t == 0) stats[c] = red[0];
}

__global__ void bn_finalize(const float* __restrict__ colsum, const float* __restrict__ colsumsq,
                            const float* __restrict__ gamma, const float* __restrict__ beta,
                            float* __restrict__ scale, float* __restrict__ shift, float invN) {
    int c = threadIdx.x;
    float mu = colsum[c] * invN;
    float var = colsumsq[c] * invN - mu * mu;
    float sc = gamma[c] / sqrtf(var + 1e-5f);
    scale[c] = sc;
    shift[c] = beta[c] - mu * sc;
}

// x -> bn -> bf16 ; noise -> bf16. One pass, float4 in / ushort4 out.
__global__ void convert_inputs(const float4* __restrict__ x4, const float4* __restrict__ n4,
                               const float* __restrict__ scale, const float* __restrict__ shift,
                               ushort4* __restrict__ xb, ushort4* __restrict__ nb, int total4) {
    int i = blockIdx.x * blockDim.x + threadIdx.x;
    if (i >= total4) return;
    int c4 = (i & 31) << 2;
    float4 sc = *reinterpret_cast<const float4*>(scale + c4);
    float4 sh = *reinterpret_cast<const float4*>(shift + c4);
    float4 v = x4[i];
    ushort4 o;
    o.x = f2bf(fmaf(v.x, sc.x, sh.x));
    o.y = f2bf(fmaf(v.y, sc.y, sh.y));
    o.z = f2bf(fmaf(v.z, sc.z, sh.z));
    o.w = f2bf(fmaf(v.w, sc.w, sh.w));
    xb[i] = o;
    float4 w = n4[i];
    ushort4 p;
    p.x = f2bf(w.x); p.y = f2bf(w.y); p.z = f2bf(w.z); p.w = f2bf(w.w);
    nb[i] = p;
}

// Wt[c][k] = bf16(W[k][c]); Wt row stride = K
__global__ void transpose_w(const float* __restrict__ W, unsigned short* __restrict__ Wt,
                            int K, int C) {
    int i = blockIdx.x * blockDim.x + threadIdx.x;
    if (i >= K * C) return;
    int k = i / C, c = i % C;
    Wt[(size_t)c * K + k] = f2bf(W[i]);
}

// ---------------------------------------------------------------------------
// MFMA GEMM: hs[MP x 128] = (sum_s A_s[MP x 128] @ W[s*128:, :]) * dinv[row]
// Block 64 rows x 128 cols, 4 waves 2x2; wave tile 32 rows x 64 cols.
// A-tile [64r][128k] staged to LDS by global_load_lds (16B), double-buffered
// across sources. Granule swizzle g ^= (row&7): LDS dest stays LINEAR
// (base+lane*16), the global SOURCE address is pre-swizzled, and the
// ds_read applies the same XOR -> conflict-free b128 reads (rule #21).
// ---------------------------------------------------------------------------
template <int NSRC>
__global__ __launch_bounds__(256, 4) void gemm_mfma(
    const unsigned short* __restrict__ A0, const unsigned short* __restrict__ A1,
    const unsigned short* __restrict__ A2,
    const unsigned short* __restrict__ Wt,   // [128 cols][NSRC*128 k]
    const float* __restrict__ dinv, unsigned short* __restrict__ out)
{
    constexpr int KTOT = NSRC * 128;
    constexpr int NBUF = (NSRC > 1) ? 2 : 1;
    __shared__ unsigned char ldsA[NBUF][64 * 256];   // [rows][128k * 2B]

    const int lane = threadIdx.x & 63;
    const int wid  = threadIdx.x >> 6;
    const int wr   = wid >> 1, wc = wid & 1;
    const int l15  = lane & 15, lhi = lane >> 4;
    const int c0   = wc * 64;
    const long rowblk = (long)blockIdx.x * 64;
    const int rl0 = wr * 32 + l15;      // local rows this lane covers
    const int rl1 = rl0 + 16;
    const int rsw = rl0 & 7;            // same for rl1 (+16)

    // staging lambda: wave wid stages granules G = (wid*4+i)*64 + lane
    const unsigned short* __restrict__ srcs[3] = {A0, A1, A2};
    auto stage = [&](int s, int b) {
#pragma unroll
        for (int i = 0; i < 4; i++) {
            int G = (wid * 4 + i) * 64 + lane;   // 0..1023 granules of 16B
            int r = G >> 4, g = G & 15;
            const unsigned short* src = srcs[s] + (rowblk + r) * 128 + (g ^ (r & 7)) * 8;
            gload_lds16(src, &ldsA[b][G * 16]);
        }
    };

    f32x4 acc[2][4];
#pragma unroll
    for (int g = 0; g < 2; g++)
#pragma unroll
        for (int n = 0; n < 4; n++)
            acc[g][n] = (f32x4){0.f, 0.f, 0.f, 0.f};

    stage(0, 0);

#pragma unroll
    for (int s = 0; s < NSRC; s++) {
        __syncthreads();                         // buf[s%NBUF] staged (vmcnt drain)
        if (s + 1 < NSRC) stage(s + 1, (s + 1) % NBUF);
        const unsigned char* bufp = ldsA[s % NBUF];
        const unsigned short* wp = Wt + (size_t)(c0 + l15) * KTOT + s * 128 + lhi * 8;

        bf16x8 w[4], wn[4];
#pragma unroll
        for (int n = 0; n < 4; n++)
            w[n] = *reinterpret_cast<const bf16x8*>(wp + (size_t)(n * 16) * KTOT);
#pragma unroll
        for (int kc = 0; kc < 4; kc++) {
            int g0 = kc * 4 + lhi;
            bf16x8 a0 = *reinterpret_cast<const bf16x8*>(bufp + rl0 * 256 + (g0 ^ rsw) * 16);
            bf16x8 a1 = *reinterpret_cast<const bf16x8*>(bufp + rl1 * 256 + (g0 ^ rsw) * 16);
            if (kc < 3) {
#pragma unroll
                for (int n = 0; n < 4; n++)
                    wn[n] = *reinterpret_cast<const bf16x8*>(wp + (kc + 1) * 32 +
                                                             (size_t)(n * 16) * KTOT);
            }
#pragma unroll
            for (int n = 0; n < 4; n++) {
                acc[0][n] = __builtin_amdgcn_mfma_f32_16x16x32_bf16(w[n], a0, acc[0][n], 0, 0, 0);
                acc[1][n] = __builtin_amdgcn_mfma_f32_16x16x32_bf16(w[n], a1, acc[1][n], 0, 0, 0);
            }
            if (kc < 3) {
#pragma unroll
                for (int n = 0; n < 4; n++) w[n] = wn[n];
            }
        }
    }

#pragma unroll
    for (int g = 0; g < 2; g++) {
        long row = rowblk + (g ? rl1 : rl0);
        float dv = dinv[row];
        unsigned short* op = out + row * 128 + c0 + lhi * 4;
#pragma unroll
        for (int n = 0; n < 4; n++) {
            f32x4 v = acc[g][n];
            ushort4 pk;
            pk.x = f2bf(v[0] * dv);
            pk.y = f2bf(v[1] * dv);
            pk.z = f2bf(v[2] * dv);
            pk.w = f2bf(v[3] * dv);
            *reinterpret_cast<ushort4*>(op + n * 16) = pk;
        }
    }
}

// ---------------------------------------------------------------------------
// CSR gather: one wave per node; 16 lanes x uint4 (16B) cover one 256B row;
// 4 sub-groups stride the edge list; cross-sub shuffle reduce at the end.
// ---------------------------------------------------------------------------
template <bool RELU>
__global__ void gather16(const uint4* __restrict__ hs4, const float* __restrict__ dinv,
                         const int* __restrict__ row_ptr, const int* __restrict__ edge_src,
                         const float* __restrict__ bias, uint4* __restrict__ out4, int n) {
    int node = blockIdx.x * 4 + (threadIdx.x >> 6);
    if (node >= n) return;
    int lane = threadIdx.x & 63;
    int cl = lane & 15, sub = lane >> 4;
    int beg = row_ptr[node], end = row_ptr[node + 1];
    float a0[8] = {0.f,0.f,0.f,0.f,0.f,0.f,0.f,0.f};
    float a1[8] = {0.f,0.f,0.f,0.f,0.f,0.f,0.f,0.f};
    if (sub == 0) acc8(a0, hs4[(size_t)node * 16 + cl]);   // self-loop
    int e = beg + sub;
    for (; e + 4 < end; e += 8) {
        uint4 v0 = hs4[(size_t)edge_src[e] * 16 + cl];
        uint4 v1 = hs4[(size_t)edge_src[e + 4] * 16 + cl];
        acc8(a0, v0);
        acc8(a1, v1);
    }
    if (e < end) acc8(a0, hs4[(size_t)edge_src[e] * 16 + cl]);
#pragma unroll
    for (int i = 0; i < 8; i++) a0[i] += a1[i];
#pragma unroll
    for (int i = 0; i < 8; i++) {
        a0[i] += __shfl_xor(a0[i], 16);
        a0[i] += __shfl_xor(a0[i], 32);
    }
    if (sub == 0) {
        float dv = dinv[node];
        float4 b0 = *reinterpret_cast<const float4*>(bias + cl * 8);
        float4 b1 = *reinterpret_cast<const float4*>(bias + cl * 8 + 4);
        float r0 = fmaf(a0[0], dv, b0.x), r1 = fmaf(a0[1], dv, b0.y);
        float r2 = fmaf(a0[2], dv, b0.z), r3 = fmaf(a0[3], dv, b0.w);
        float r4 = fmaf(a0[4], dv, b1.x), r5 = fmaf(a0[5], dv, b1.y);
        float r6 = fmaf(a0[6], dv, b1.z), r7 = fmaf(a0[7], dv, b1.w);
        if (RELU) {
            r0 = fmaxf(r0, 0.f); r1 = fmaxf(r1, 0.f); r2 = fmaxf(r2, 0.f); r3 = fmaxf(r3, 0.f);
            r4 = fmaxf(r4, 0.f); r5 = fmaxf(r5, 0.f); r6 = fmaxf(r6, 0.f); r7 = fmaxf(r7, 0.f);
        }
        uint4 o;
        o.x = pack2(r0, r1); o.y = pack2(r2, r3);
        o.z = pack2(r4, r5); o.w = pack2(r6, r7);
        out4[(size_t)node * 16 + cl] = o;
    }
}

// final: t rows = [tm(64) | ts(64)] bf16 -> zm, zs fp32
__global__ void gather_dual(const uint4* __restrict__ hs4, const float* __restrict__ dinv,
                            const int* __restrict__ row_ptr, const int* __restrict__ edge_src,
                            const float* __restrict__ bm, const float* __restrict__ bs,
                            float* __restrict__ zm, float* __restrict__ zs, int n) {
    int node = blockIdx.x * 4 + (threadIdx.x >> 6);
    if (node >= n) return;
    int lane = threadIdx.x & 63;
    int cl = lane & 15, sub = lane >> 4;
    int beg = row_ptr[node], end = row_ptr[node + 1];
    float a0[8] = {0.f,0.f,0.f,0.f,0.f,0.f,0.f,0.f};
    float a1[8] = {0.f,0.f,0.f,0.f,0.f,0.f,0.f,0.f};
    if (sub == 0) acc8(a0, hs4[(size_t)node * 16 + cl]);
    int e = beg + sub;
    for (; e + 4 < end; e += 8) {
        uint4 v0 = hs4[(size_t)edge_src[e] * 16 + cl];
        uint4 v1 = hs4[(size_t)edge_src[e + 4] * 16 + cl];
        acc8(a0, v0);
        acc8(a1, v1);
    }
    if (e < end) acc8(a0, hs4[(size_t)edge_src[e] * 16 + cl]);
#pragma unroll
    for (int i = 0; i < 8; i++) a0[i] += a1[i];
#pragma unroll
    for (int i = 0; i < 8; i++) {
        a0[i] += __shfl_xor(a0[i], 16);
        a0[i] += __shfl_xor(a0[i], 32);
    }
    if (sub == 0) {
        float dv = dinv[node];
        const float* bp = (cl < 8) ? (bm + cl * 8) : (bs + (cl - 8) * 8);
        float* zp = (cl < 8) ? (zm + (size_t)node * 64 + cl * 8)
                             : (zs + (size_t)node * 64 + (cl - 8) * 8);
        float4 b0 = *reinterpret_cast<const float4*>(bp);
        float4 b1 = *reinterpret_cast<const float4*>(bp + 4);
        float4 o0 = make_float4(fmaf(a0[0], dv, b0.x), fmaf(a0[1], dv, b0.y),
                                fmaf(a0[2], dv, b0.z), fmaf(a0[3], dv, b0.w));
        float4 o1 = make_float4(fmaf(a0[4], dv, b1.x), fmaf(a0[5], dv, b1.y),
                                fmaf(a0[6], dv, b1.z), fmaf(a0[7], dv, b1.w));
        *reinterpret_cast<float4*>(zp) = o0;
        *reinterpret_cast<float4*>(zp + 4) = o1;
    }
}

// ---------------------------------------------------------------------------

extern "C" void kernel_launch(void* const* d_in, const int* in_sizes, int n_in,
                              void* d_out, int out_size, void* d_ws, size_t ws_size,
                              hipStream_t stream) {
    const float* x     = (const float*)d_in[0];
    const float* noise = (const float*)d_in[1];
    const int*   ei    = (const int*)d_in[2];
    const float* gamma = (const float*)d_in[3];
    const float* beta  = (const float*)d_in[4];
    const float* W1    = (const float*)d_in[5];
    const float* b1    = (const float*)d_in[6];
    const float* W2    = (const float*)d_in[7];
    const float* b2    = (const float*)d_in[8];
    const float* Wm    = (const float*)d_in[9];
    const float* bm    = (const float*)d_in[10];
    const float* Ws    = (const float*)d_in[11];
    const float* bs    = (const float*)d_in[12];

    const int N  = in_sizes[0] / 128;
    const int E  = in_sizes[2] / 2;
    const int NPAD = (N + 127) & ~127;        // row-padded size for GEMM buffers
    const int nb = (N + SCAN_ELEMS - 1) / SCAN_ELEMS;

    auto align256 = [](size_t b) { return (b + 255) & ~(size_t)255; };
    char* p = (char*)d_ws;
    int* cnt      = (int*)p;  p += align256((size_t)N * 4);
    int* row_ptr  = (int*)p;  p += align256((size_t)(N + 1) * 4);
    int* edge_src = (int*)p;  p += align256((size_t)E * 4);
    int* bsums    = (int*)p;  p += align256((size_t)nb * 4);
    float* dinv   = (float*)p; p += align256((size_t)NPAD * 4);
    float* stats  = (float*)p; p += align256(512 * 4);
    float* bnpart = (float*)p; p += align256((size_t)256 * BN_G * 4);
    unsigned short* Wt1 = (unsigned short*)p; p += align256(128 * 128 * 2);
    unsigned short* Wt2 = (unsigned short*)p; p += align256(128 * 384 * 2);
    unsigned short* Wtc = (unsigned short*)p; p += align256(128 * 256 * 2);
    unsigned short* xb16 = (unsigned short*)p; p += align256((size_t)NPAD * 128 * 2);
    unsigned short* n16  = (unsigned short*)p; p += align256((size_t)NPAD * 128 * 2);  // noise, then hs3
    unsigned short* h16  = (unsigned short*)p; p += align256((size_t)NPAD * 128 * 2);  // h1, then h2

    float* colsum   = stats;
    float* colsumsq = stats + 128;
    float* scale    = stats + 256;
    float* shift    = stats + 384;

    float* dout = (float*)d_out;                       // N*128 fp32
    unsigned short* hs12 = (unsigned short*)d_out;     // conv1/2 hs scratch (bf16, NPAD rows fit)
    unsigned short* hs3  = n16;                        // noise dead after conv2
    float* zm = dout;                                  // [N*64]
    float* zs = dout + (size_t)N * 64;                 // [N*64]

    const int gblocks = NPAD / 64;
    const int nblocks4 = (N + 3) / 4;

    // --- graph structure + BN stats + conversions ---
    zero_i32<<<(N + 255) / 256, 256, 0, stream>>>(cnt, N);
    count_deg<<<(E + 255) / 256, 256, 0, stream>>>(ei, cnt, E);
    bn_stats<<<BN_G, 256, 0, stream>>>((const float4*)x, bnpart, N);
    bn_reduce<<<256, 256, 0, stream>>>((const float4*)bnpart, stats);
    bn_finalize<<<1, 128, 0, stream>>>(colsum, colsumsq, gamma, beta, scale, shift, 1.0f / (float)N);
    scan_blocks<<<nb, SCAN_BLK, 0, stream>>>(cnt, row_ptr, bsums, N);
    scan_bsums<<<1, 64, 0, stream>>>(bsums, nb);
    scan_add<<<(N + 255) / 256, 256, 0, stream>>>(row_ptr, bsums, N, E);
    dinv_from_cnt<<<(N + 255) / 256, 256, 0, stream>>>(cnt, dinv, N);
    fill_edges<<<(E + 255) / 256, 256, 0, stream>>>(ei, row_ptr, cnt, edge_src, E);
    convert_inputs<<<(N * 32 + 255) / 256, 256, 0, stream>>>(
        (const float4*)x, (const float4*)noise, scale, shift,
        (ushort4*)xb16, (ushort4*)n16, N * 32);
    transpose_w<<<(128 * 128 + 255) / 256, 256, 0, stream>>>(W1, Wt1, 128, 128);
    transpose_w<<<(384 * 128 + 255) / 256, 256, 0, stream>>>(W2, Wt2, 384, 128);
    transpose_w<<<(256 * 64 + 255) / 256, 256, 0, stream>>>(Wm, Wtc, 256, 64);
    transpose_w<<<(256 * 64 + 255) / 256, 256, 0, stream>>>(Ws, Wtc + 64 * 256, 256, 64);

    // conv1
    gemm_mfma<1><<<gblocks, 256, 0, stream>>>(xb16, nullptr, nullptr, Wt1, dinv, hs12);
    gather16<true><<<nblocks4, 256, 0, stream>>>((const uint4*)hs12, dinv, row_ptr,
                                                 edge_src, b1, (uint4*)h16, N);
    // conv2
    gemm_mfma<3><<<gblocks, 256, 0, stream>>>(xb16, n16, h16, Wt2, dinv, hs12);
    gather16<true><<<nblocks4, 256, 0, stream>>>((const uint4*)hs12, dinv, row_ptr,
                                                 edge_src, b2, (uint4*)h16, N);
    // mean/logstd fused (hs -> n16 slot; d_out now gets final fp32 outputs)
    gemm_mfma<2><<<gblocks, 256, 0, stream>>>(xb16, h16, nullptr, Wtc, dinv, hs3);
    gather_dual<<<nblocks4, 256, 0, stream>>>((const uint4*)hs3, dinv, row_ptr,
                                              edge_src, bm, bs, zm, zs, N);
}

// Round 9
// 396.426 us; speedup vs baseline: 1.0576x; 1.0219x over previous
//
#include <hip/hip_runtime.h>
#include <math.h>

// ---------------------------------------------------------------------------
// GCN encoder forward, bf16 MFMA formulation:
//   CSR build (hist->scan->fill) ; BN stats (fp32, partials + reduce)
//   xb16 = bn(x) in bf16 ; noise16 = bf16(noise) ; Wt = W^T in bf16
//   hs16 = (concat srcs @ W) * dinv[row]   (MFMA gemm, bf16 out)
//   out[d] = act(dinv[d]*(sum_in hs16[src] + hs16[d]) + bias)
// GEMM: A staged to LDS via global_load_lds; W fragments preloaded to regs
// BEFORE the barrier and BEFORE stage(s+1) so the compute phase has zero
// vmem dependencies -> stage(s+1) truly overlaps compute(s) (vmcnt is FIFO).
// ---------------------------------------------------------------------------

typedef short bf16x8 __attribute__((ext_vector_type(8)));
typedef float f32x4 __attribute__((ext_vector_type(4)));

#define BN_G 1024

__device__ inline unsigned short f2bf(float f) {  // RNE
    unsigned int u = __builtin_bit_cast(unsigned int, f);
    u += 0x7fff + ((u >> 16) & 1);
    return (unsigned short)(u >> 16);
}
__device__ inline float bfl(unsigned int u) { return __builtin_bit_cast(float, u << 16); }
__device__ inline float bfh(unsigned int u) { return __builtin_bit_cast(float, u & 0xffff0000u); }
__device__ inline unsigned int pack2(float lo, float hi) {
    return ((unsigned int)f2bf(hi) << 16) | f2bf(lo);
}
__device__ inline void acc8(float* a, uint4 v) {
    a[0] += bfl(v.x); a[1] += bfh(v.x);
    a[2] += bfl(v.y); a[3] += bfh(v.y);
    a[4] += bfl(v.z); a[5] += bfh(v.z);
    a[6] += bfl(v.w); a[7] += bfh(v.w);
}

__device__ __forceinline__ void gload_lds16(const void* g, void* l) {
    __builtin_amdgcn_global_load_lds(
        (const __attribute__((address_space(1))) unsigned int*)g,
        (__attribute__((address_space(3))) unsigned int*)l, 16, 0, 0);
}

__global__ void zero_i32(int* __restrict__ p, int n) {
    int i = blockIdx.x * blockDim.x + threadIdx.x;
    if (i < n) p[i] = 0;
}

__global__ void count_deg(const int* __restrict__ ei, int* __restrict__ cnt, int E) {
    int e = blockIdx.x * blockDim.x + threadIdx.x;
    if (e < E) atomicAdd(&cnt[ei[E + e]], 1);
}

__global__ void dinv_from_cnt(const int* __restrict__ cnt, float* __restrict__ dinv, int n) {
    int i = blockIdx.x * blockDim.x + threadIdx.x;
    if (i < n) dinv[i] = rsqrtf((float)cnt[i] + 1.0f);   // +1 self-loop
}

#define SCAN_BLK 256
#define SCAN_ELEMS 1024

__global__ void scan_blocks(const int* __restrict__ cnt, int* __restrict__ out,
                            int* __restrict__ bsums, int n) {
    __shared__ int lds[SCAN_BLK];
    int base = blockIdx.x * SCAN_ELEMS;
    int t = threadIdx.x;
    int v[4];
    int s = 0;
#pragma unroll
    for (int j = 0; j < 4; j++) {
        int i = base + t * 4 + j;
        v[j] = s;
        s += (i < n) ? cnt[i] : 0;
    }
    lds[t] = s;
    __syncthreads();
    for (int off = 1; off < SCAN_BLK; off <<= 1) {
        int val = (t >= off) ? lds[t - off] : 0;
        __syncthreads();
        lds[t] += val;
        __syncthreads();
    }
    int excl = (t == 0) ? 0 : lds[t - 1];
#pragma unroll
    for (int j = 0; j < 4; j++) {
        int i = base + t * 4 + j;
        if (i < n) out[i] = excl + v[j];
    }
    if (t == SCAN_BLK - 1) bsums[blockIdx.x] = lds[t];
}

__global__ void scan_bsums(int* __restrict__ bsums, int nb) {
    if (threadIdx.x == 0 && blockIdx.x == 0) {
        int acc = 0;
        for (int i = 0; i < nb; i++) { int c = bsums[i]; bsums[i] = acc; acc += c; }
    }
}

__global__ void scan_add(int* __restrict__ row_ptr, const int* __restrict__ bsums, int n, int E) {
    int i = blockIdx.x * blockDim.x + threadIdx.x;
    if (i < n) row_ptr[i] += bsums[i / SCAN_ELEMS];
    if (i == 0) row_ptr[n] = E;
}

__global__ void fill_edges(const int* __restrict__ ei, const int* __restrict__ row_ptr,
                           int* __restrict__ cnt, int* __restrict__ edge_src, int E) {
    int e = blockIdx.x * blockDim.x + threadIdx.x;
    if (e >= E) return;
    int s = ei[e], d = ei[E + e];
    int off = atomicSub(&cnt[d], 1) - 1;
    edge_src[row_ptr[d] + off] = s;
}

// ---- BN statistics: 4-deep row unroll, non-atomic partials ----------------
__global__ __launch_bounds__(256) void bn_stats(const float4* __restrict__ x4,
                                                float* __restrict__ partials, int n) {
    int t = threadIdx.x;
    int cg = t & 31;          // column group (float4)
    int rs = t >> 5;          // row slice 0..7, 4 rows each
    float4 s = make_float4(0.f, 0.f, 0.f, 0.f);
    float4 q = make_float4(0.f, 0.f, 0.f, 0.f);
    const float4 z4 = make_float4(0.f, 0.f, 0.f, 0.f);
    const int stride = BN_G * 32;
    for (int r0 = blockIdx.x * 32 + rs * 4; r0 < n; r0 += stride) {
        float4 v0 = x4[(size_t)r0 * 32 + cg];
        float4 v1 = (r0 + 1 < n) ? x4[(size_t)(r0 + 1) * 32 + cg] : z4;
        float4 v2 = (r0 + 2 < n) ? x4[(size_t)(r0 + 2) * 32 + cg] : z4;
        float4 v3 = (r0 + 3 < n) ? x4[(size_t)(r0 + 3) * 32 + cg] : z4;
        s.x += v0.x + v1.x + v2.x + v3.x;
        s.y += v0.y + v1.y + v2.y + v3.y;
        s.z += v0.z + v1.z + v2.z + v3.z;
        s.w += v0.w + v1.w + v2.w + v3.w;
        q.x = fmaf(v0.x, v0.x, fmaf(v1.x, v1.x, fmaf(v2.x, v2.x, fmaf(v3.x, v3.x, q.x))));
        q.y = fmaf(v0.y, v0.y, fmaf(v1.y, v1.y, fmaf(v2.y, v2.y, fmaf(v3.y, v3.y, q.y))));
        q.z = fmaf(v0.z, v0.z, fmaf(v1.z, v1.z, fmaf(v2.z, v2.z, fmaf(v3.z, v3.z, q.z))));
        q.w = fmaf(v0.w, v0.w, fmaf(v1.w, v1.w, fmaf(v2.w, v2.w, fmaf(v3.w, v3.w, q.w))));
    }
    __shared__ float4 lds[2][8][32];
    lds[0][rs][cg] = s;
    lds[1][rs][cg] = q;
    __syncthreads();
    if (t < 64) {
        int which = t >> 5;   // 0: sum, 1: sumsq
        int c = t & 31;
        float4 a = lds[which][0][c];
#pragma unroll
        for (int i = 1; i < 8; i++) {
            float4 b = lds[which][i][c];
            a.x += b.x; a.y += b.y; a.z += b.z; a.w += b.w;
        }
        int base = which * 128 + c * 4;
        partials[(size_t)(base + 0) * BN_G + blockIdx.x] = a.x;
        partials[(size_t)(base + 1) * BN_G + blockIdx.x] = a.y;
        partials[(size_t)(base + 2) * BN_G + blockIdx.x] = a.z;
        partials[(size_t)(base + 3) * BN_G + blockIdx.x] = a.w;
    }
}

// one block per output element c in [0,256): stats[c] = sum over BN_G partials
__global__ void bn_reduce(const float4* __restrict__ partials4, float* __restrict__ stats) {
    __shared__ float red[256];
    int c = blockIdx.x, t = threadIdx.x;
    float4 v = partials4[(size_t)c * (BN_G / 4) + t];
    red[t] = v.x + v.y + v.z + v.w;
    __syncthreads();
    for (int off = 128; off > 0; off >>= 1) {
        if (t < off) red[t] += red[t + off];
        __syncthreads();
    }
    if (t == 0) stats[c] = red[0];
}

__global__ void bn_finalize(const float* __restrict__ colsum, const float* __restrict__ colsumsq,
                            const float* __restrict__ gamma, const float* __restrict__ beta,
                            float* __restrict__ scale, float* __restrict__ shift, float invN) {
    int c = threadIdx.x;
    float mu = colsum[c] * invN;
    float var = colsumsq[c] * invN - mu * mu;
    float sc = gamma[c] / sqrtf(var + 1e-5f);
    scale[c] = sc;
    shift[c] = beta[c] - mu * sc;
}

// x -> bn -> bf16 ; noise -> bf16. One pass, float4 in / ushort4 out.
__global__ void convert_inputs(const float4* __restrict__ x4, const float4* __restrict__ n4,
                               const float* __restrict__ scale, const float* __restrict__ shift,
                               ushort4* __restrict__ xb, ushort4* __restrict__ nb, int total4) {
    int i = blockIdx.x * blockDim.x + threadIdx.x;
    if (i >= total4) return;
    int c4 = (i & 31) << 2;
    float4 sc = *reinterpret_cast<const float4*>(scale + c4);
    float4 sh = *reinterpret_cast<const float4*>(shift + c4);
    float4 v = x4[i];
    ushort4 o;
    o.x = f2bf(fmaf(v.x, sc.x, sh.x));
    o.y = f2bf(fmaf(v.y, sc.y, sh.y));
    o.z = f2bf(fmaf(v.z, sc.z, sh.z));
    o.w = f2bf(fmaf(v.w, sc.w, sh.w));
    xb[i] = o;
    float4 w = n4[i];
    ushort4 p;
    p.x = f2bf(w.x); p.y = f2bf(w.y); p.z = f2bf(w.z); p.w = f2bf(w.w);
    nb[i] = p;
}

// Wt[c][k] = bf16(W[k][c]); Wt row stride = K
__global__ void transpose_w(const float* __restrict__ W, unsigned short* __restrict__ Wt,
                            int K, int C) {
    int i = blockIdx.x * blockDim.x + threadIdx.x;
    if (i >= K * C) return;
    int k = i / C, c = i % C;
    Wt[(size_t)c * K + k] = f2bf(W[i]);
}

// ---------------------------------------------------------------------------
// MFMA GEMM: hs[MP x 128] = (sum_s A_s[MP x 128] @ W[s*128:, :]) * dinv[row]
// Block 64 rows x 128 cols, 4 waves 2x2; wave tile 32 rows x 64 cols.
// Per source s: [preload 16 W-frags to regs] -> syncthreads (drains stage(s)
// AND W together) -> issue stage(s+1) -> compute from LDS+regs only.
// Compute phase has no vmem dependency => stage(s+1) overlaps compute(s).
// ---------------------------------------------------------------------------
template <int NSRC>
__global__ __launch_bounds__(256, 4) void gemm_mfma(
    const unsigned short* __restrict__ A0, const unsigned short* __restrict__ A1,
    const unsigned short* __restrict__ A2,
    const unsigned short* __restrict__ Wt,   // [128 cols][NSRC*128 k]
    const float* __restrict__ dinv, unsigned short* __restrict__ out)
{
    constexpr int KTOT = NSRC * 128;
    constexpr int NBUF = (NSRC > 1) ? 2 : 1;
    __shared__ unsigned char ldsA[NBUF][64 * 256];   // [rows][128k * 2B]

    const int lane = threadIdx.x & 63;
    const int wid  = threadIdx.x >> 6;
    const int wr   = wid >> 1, wc = wid & 1;
    const int l15  = lane & 15, lhi = lane >> 4;
    const int c0   = wc * 64;
    const long rowblk = (long)blockIdx.x * 64;
    const int rl0 = wr * 32 + l15;      // local rows this lane covers
    const int rl1 = rl0 + 16;
    const int rsw = rl0 & 7;            // same for rl1 (+16)

    // staging: wave wid stages granules G = (wid*4+i)*64 + lane (16B each)
    const unsigned short* __restrict__ srcs[3] = {A0, A1, A2};
    auto stage = [&](int s, int b) {
#pragma unroll
        for (int i = 0; i < 4; i++) {
            int G = (wid * 4 + i) * 64 + lane;   // 0..1023 granules of 16B
            int r = G >> 4, g = G & 15;
            const unsigned short* src = srcs[s] + (rowblk + r) * 128 + (g ^ (r & 7)) * 8;
            gload_lds16(src, &ldsA[b][G * 16]);
        }
    };

    f32x4 acc[2][4];
#pragma unroll
    for (int g = 0; g < 2; g++)
#pragma unroll
        for (int n = 0; n < 4; n++)
            acc[g][n] = (f32x4){0.f, 0.f, 0.f, 0.f};

    stage(0, 0);

#pragma unroll
    for (int s = 0; s < NSRC; s++) {
        // preload ALL W fragments for source s (global loads issued BEFORE the
        // barrier: they drain together with stage(s), hidden under its latency)
        const unsigned short* wp = Wt + (size_t)(c0 + l15) * KTOT + s * 128 + lhi * 8;
        bf16x8 w[4][4];
#pragma unroll
        for (int kc = 0; kc < 4; kc++)
#pragma unroll
            for (int n = 0; n < 4; n++)
                w[kc][n] = *reinterpret_cast<const bf16x8*>(wp + kc * 32 +
                                                            (size_t)(n * 16) * KTOT);
        __syncthreads();                         // stage(s) + W(s) complete
        if (s + 1 < NSRC) stage(s + 1, (s + 1) % NBUF);
        const unsigned char* bufp = ldsA[s % NBUF];

#pragma unroll
        for (int kc = 0; kc < 4; kc++) {
            int g0 = kc * 4 + lhi;
            bf16x8 a0 = *reinterpret_cast<const bf16x8*>(bufp + rl0 * 256 + (g0 ^ rsw) * 16);
            bf16x8 a1 = *reinterpret_cast<const bf16x8*>(bufp + rl1 * 256 + (g0 ^ rsw) * 16);
#pragma unroll
            for (int n = 0; n < 4; n++) {
                acc[0][n] = __builtin_amdgcn_mfma_f32_16x16x32_bf16(w[kc][n], a0, acc[0][n], 0, 0, 0);
                acc[1][n] = __builtin_amdgcn_mfma_f32_16x16x32_bf16(w[kc][n], a1, acc[1][n], 0, 0, 0);
            }
        }
    }

#pragma unroll
    for (int g = 0; g < 2; g++) {
        long row = rowblk + (g ? rl1 : rl0);
        float dv = dinv[row];
        unsigned short* op = out + row * 128 + c0 + lhi * 4;
#pragma unroll
        for (int n = 0; n < 4; n++) {
            f32x4 v = acc[g][n];
            ushort4 pk;
            pk.x = f2bf(v[0] * dv);
            pk.y = f2bf(v[1] * dv);
            pk.z = f2bf(v[2] * dv);
            pk.w = f2bf(v[3] * dv);
            *reinterpret_cast<ushort4*>(op + n * 16) = pk;
        }
    }
}

// ---------------------------------------------------------------------------
// CSR gather: one wave per node; 16 lanes x uint4 (16B) cover one 256B row;
// 4 sub-groups stride the edge list; cross-sub shuffle reduce at the end.
// ---------------------------------------------------------------------------
template <bool RELU>
__global__ void gather16(const uint4* __restrict__ hs4, const float* __restrict__ dinv,
                         const int* __restrict__ row_ptr, const int* __restrict__ edge_src,
                         const float* __restrict__ bias, uint4* __restrict__ out4, int n) {
    int node = blockIdx.x * 4 + (threadIdx.x >> 6);
    if (node >= n) return;
    int lane = threadIdx.x & 63;
    int cl = lane & 15, sub = lane >> 4;
    int beg = row_ptr[node], end = row_ptr[node + 1];
    float a0[8] = {0.f,0.f,0.f,0.f,0.f,0.f,0.f,0.f};
    float a1[8] = {0.f,0.f,0.f,0.f,0.f,0.f,0.f,0.f};
    if (sub == 0) acc8(a0, hs4[(size_t)node * 16 + cl]);   // self-loop
    int e = beg + sub;
    for (; e + 4 < end; e += 8) {
        uint4 v0 = hs4[(size_t)edge_src[e] * 16 + cl];
        uint4 v1 = hs4[(size_t)edge_src[e + 4] * 16 + cl];
        acc8(a0, v0);
        acc8(a1, v1);
    }
    if (e < end) acc8(a0, hs4[(size_t)edge_src[e] * 16 + cl]);
#pragma unroll
    for (int i = 0; i < 8; i++) a0[i] += a1[i];
#pragma unroll
    for (int i = 0; i < 8; i++) {
        a0[i] += __shfl_xor(a0[i], 16);
        a0[i] += __shfl_xor(a0[i], 32);
    }
    if (sub == 0) {
        float dv = dinv[node];
        float4 b0 = *reinterpret_cast<const float4*>(bias + cl * 8);
        float4 b1 = *reinterpret_cast<const float4*>(bias + cl * 8 + 4);
        float r0 = fmaf(a0[0], dv, b0.x), r1 = fmaf(a0[1], dv, b0.y);
        float r2 = fmaf(a0[2], dv, b0.z), r3 = fmaf(a0[3], dv, b0.w);
        float r4 = fmaf(a0[4], dv, b1.x), r5 = fmaf(a0[5], dv, b1.y);
        float r6 = fmaf(a0[6], dv, b1.z), r7 = fmaf(a0[7], dv, b1.w);
        if (RELU) {
            r0 = fmaxf(r0, 0.f); r1 = fmaxf(r1, 0.f); r2 = fmaxf(r2, 0.f); r3 = fmaxf(r3, 0.f);
            r4 = fmaxf(r4, 0.f); r5 = fmaxf(r5, 0.f); r6 = fmaxf(r6, 0.f); r7 = fmaxf(r7, 0.f);
        }
        uint4 o;
        o.x = pack2(r0, r1); o.y = pack2(r2, r3);
        o.z = pack2(r4, r5); o.w = pack2(r6, r7);
        out4[(size_t)node * 16 + cl] = o;
    }
}

// final: t rows = [tm(64) | ts(64)] bf16 -> zm, zs fp32
__global__ void gather_dual(const uint4* __restrict__ hs4, const float* __restrict__ dinv,
                            const int* __restrict__ row_ptr, const int* __restrict__ edge_src,
                            const float* __restrict__ bm, const float* __restrict__ bs,
                            float* __restrict__ zm, float* __restrict__ zs, int n) {
    int node = blockIdx.x * 4 + (threadIdx.x >> 6);
    if (node >= n) return;
    int lane = threadIdx.x & 63;
    int cl = lane & 15, sub = lane >> 4;
    int beg = row_ptr[node], end = row_ptr[node + 1];
    float a0[8] = {0.f,0.f,0.f,0.f,0.f,0.f,0.f,0.f};
    float a1[8] = {0.f,0.f,0.f,0.f,0.f,0.f,0.f,0.f};
    if (sub == 0) acc8(a0, hs4[(size_t)node * 16 + cl]);
    int e = beg + sub;
    for (; e + 4 < end; e += 8) {
        uint4 v0 = hs4[(size_t)edge_src[e] * 16 + cl];
        uint4 v1 = hs4[(size_t)edge_src[e + 4] * 16 + cl];
        acc8(a0, v0);
        acc8(a1, v1);
    }
    if (e < end) acc8(a0, hs4[(size_t)edge_src[e] * 16 + cl]);
#pragma unroll
    for (int i = 0; i < 8; i++) a0[i] += a1[i];
#pragma unroll
    for (int i = 0; i < 8; i++) {
        a0[i] += __shfl_xor(a0[i], 16);
        a0[i] += __shfl_xor(a0[i], 32);
    }
    if (sub == 0) {
        float dv = dinv[node];
        const float* bp = (cl < 8) ? (bm + cl * 8) : (bs + (cl - 8) * 8);
        float* zp = (cl < 8) ? (zm + (size_t)node * 64 + cl * 8)
                             : (zs + (size_t)node * 64 + (cl - 8) * 8);
        float4 b0 = *reinterpret_cast<const float4*>(bp);
        float4 b1 = *reinterpret_cast<const float4*>(bp + 4);
        float4 o0 = make_float4(fmaf(a0[0], dv, b0.x), fmaf(a0[1], dv, b0.y),
                                fmaf(a0[2], dv, b0.z), fmaf(a0[3], dv, b0.w));
        float4 o1 = make_float4(fmaf(a0[4], dv, b1.x), fmaf(a0[5], dv, b1.y),
                                fmaf(a0[6], dv, b1.z), fmaf(a0[7], dv, b1.w));
        *reinterpret_cast<float4*>(zp) = o0;
        *reinterpret_cast<float4*>(zp + 4) = o1;
    }
}

// ---------------------------------------------------------------------------

extern "C" void kernel_launch(void* const* d_in, const int* in_sizes, int n_in,
                              void* d_out, int out_size, void* d_ws, size_t ws_size,
                              hipStream_t stream) {
    const float* x     = (const float*)d_in[0];
    const float* noise = (const float*)d_in[1];
    const int*   ei    = (const int*)d_in[2];
    const float* gamma = (const float*)d_in[3];
    const float* beta  = (const float*)d_in[4];
    const float* W1    = (const float*)d_in[5];
    const float* b1    = (const float*)d_in[6];
    const float* W2    = (const float*)d_in[7];
    const float* b2    = (const float*)d_in[8];
    const float* Wm    = (const float*)d_in[9];
    const float* bm    = (const float*)d_in[10];
    const float* Ws    = (const float*)d_in[11];
    const float* bs    = (const float*)d_in[12];

    const int N  = in_sizes[0] / 128;
    const int E  = in_sizes[2] / 2;
    const int NPAD = (N + 127) & ~127;        // row-padded size for GEMM buffers
    const int nb = (N + SCAN_ELEMS - 1) / SCAN_ELEMS;

    auto align256 = [](size_t b) { return (b + 255) & ~(size_t)255; };
    char* p = (char*)d_ws;
    int* cnt      = (int*)p;  p += align256((size_t)N * 4);
    int* row_ptr  = (int*)p;  p += align256((size_t)(N + 1) * 4);
    int* edge_src = (int*)p;  p += align256((size_t)E * 4);
    int* bsums    = (int*)p;  p += align256((size_t)nb * 4);
    float* dinv   = (float*)p; p += align256((size_t)NPAD * 4);
    float* stats  = (float*)p; p += align256(512 * 4);
    float* bnpart = (float*)p; p += align256((size_t)256 * BN_G * 4);
    unsigned short* Wt1 = (unsigned short*)p; p += align256(128 * 128 * 2);
    unsigned short* Wt2 = (unsigned short*)p; p += align256(128 * 384 * 2);
    unsigned short* Wtc = (unsigned short*)p; p += align256(128 * 256 * 2);
    unsigned short* xb16 = (unsigned short*)p; p += align256((size_t)NPAD * 128 * 2);
    unsigned short* n16  = (unsigned short*)p; p += align256((size_t)NPAD * 128 * 2);  // noise, then hs3
    unsigned short* h16  = (unsigned short*)p; p += align256((size_t)NPAD * 128 * 2);  // h1, then h2

    float* colsum   = stats;
    float* colsumsq = stats + 128;
    float* scale    = stats + 256;
    float* shift    = stats + 384;

    float* dout = (float*)d_out;                       // N*128 fp32
    unsigned short* hs12 = (unsigned short*)d_out;     // conv1/2 hs scratch (bf16, NPAD rows fit)
    unsigned short* hs3  = n16;                        // noise dead after conv2
    float* zm = dout;                                  // [N*64]
    float* zs = dout + (size_t)N * 64;                 // [N*64]

    const int gblocks = NPAD / 64;
    const int nblocks4 = (N + 3) / 4;

    // --- graph structure + BN stats + conversions ---
    zero_i32<<<(N + 255) / 256, 256, 0, stream>>>(cnt, N);
    count_deg<<<(E + 255) / 256, 256, 0, stream>>>(ei, cnt, E);
    bn_stats<<<BN_G, 256, 0, stream>>>((const float4*)x, bnpart, N);
    bn_reduce<<<256, 256, 0, stream>>>((const float4*)bnpart, stats);
    bn_finalize<<<1, 128, 0, stream>>>(colsum, colsumsq, gamma, beta, scale, shift, 1.0f / (float)N);
    scan_blocks<<<nb, SCAN_BLK, 0, stream>>>(cnt, row_ptr, bsums, N);
    scan_bsums<<<1, 64, 0, stream>>>(bsums, nb);
    scan_add<<<(N + 255) / 256, 256, 0, stream>>>(row_ptr, bsums, N, E);
    dinv_from_cnt<<<(N + 255) / 256, 256, 0, stream>>>(cnt, dinv, N);
    fill_edges<<<(E + 255) / 256, 256, 0, stream>>>(ei, row_ptr, cnt, edge_src, E);
    convert_inputs<<<(N * 32 + 255) / 256, 256, 0, stream>>>(
        (const float4*)x, (const float4*)noise, scale, shift,
        (ushort4*)xb16, (ushort4*)n16, N * 32);
    transpose_w<<<(128 * 128 + 255) / 256, 256, 0, stream>>>(W1, Wt1, 128, 128);
    transpose_w<<<(384 * 128 + 255) / 256, 256, 0, stream>>>(W2, Wt2, 384, 128);
    transpose_w<<<(256 * 64 + 255) / 256, 256, 0, stream>>>(Wm, Wtc, 256, 64);
    transpose_w<<<(256 * 64 + 255) / 256, 256, 0, stream>>>(Ws, Wtc + 64 * 256, 256, 64);

    // conv1
    gemm_mfma<1><<<gblocks, 256, 0, stream>>>(xb16, nullptr, nullptr, Wt1, dinv, hs12);
    gather16<true><<<nblocks4, 256, 0, stream>>>((const uint4*)hs12, dinv, row_ptr,
                                                 edge_src, b1, (uint4*)h16, N);
    // conv2
    gemm_mfma<3><<<gblocks, 256, 0, stream>>>(xb16, n16, h16, Wt2, dinv, hs12);
    gather16<true><<<nblocks4, 256, 0, stream>>>((const uint4*)hs12, dinv, row_ptr,
                                                 edge_src, b2, (uint4*)h16, N);
    // mean/logstd fused (hs -> n16 slot; d_out now gets final fp32 outputs)
    gemm_mfma<2><<<gblocks, 256, 0, stream>>>(xb16, h16, nullptr, Wtc, dinv, hs3);
    gather_dual<<<nblocks4, 256, 0, stream>>>((const uint4*)hs3, dinv, row_ptr,
                                              edge_src, bm, bs, zm, zs, N);
}

// Round 10
// 353.489 us; speedup vs baseline: 1.1861x; 1.1215x over previous
//
#include <hip/hip_runtime.h>
#include <math.h>

// ---------------------------------------------------------------------------
// GCN encoder forward, bf16 MFMA formulation:
//   CSR build (hist->scan->fill) ; BN stats (fp32, partials + reduce)
//   xb16 = bn(x) in bf16 ; noise16 = bf16(noise)
//   W pre-packed into MFMA-fragment layout (contiguous 1KB per fragment)
//   hs16 = (concat srcs @ W) * dinv[row]   (MFMA gemm, bf16 out)
//   out[d] = act(dinv[d]*(sum_in hs16[src] + hs16[d]) + bias)
// GEMM: A staged to LDS via global_load_lds (swizzled, dbuf across sources);
// W fragments load as wave-coalesced 1KB blocks (identical address across
// blocks -> L2 broadcast), fixing the 16-way-split W transactions of r8/r9.
// ---------------------------------------------------------------------------

typedef short bf16x8 __attribute__((ext_vector_type(8)));
typedef float f32x4 __attribute__((ext_vector_type(4)));

#define BN_G 1024

__device__ inline unsigned short f2bf(float f) {  // RNE
    unsigned int u = __builtin_bit_cast(unsigned int, f);
    u += 0x7fff + ((u >> 16) & 1);
    return (unsigned short)(u >> 16);
}
__device__ inline float bfl(unsigned int u) { return __builtin_bit_cast(float, u << 16); }
__device__ inline float bfh(unsigned int u) { return __builtin_bit_cast(float, u & 0xffff0000u); }
__device__ inline unsigned int pack2(float lo, float hi) {
    return ((unsigned int)f2bf(hi) << 16) | f2bf(lo);
}
__device__ inline void acc8(float* a, uint4 v) {
    a[0] += bfl(v.x); a[1] += bfh(v.x);
    a[2] += bfl(v.y); a[3] += bfh(v.y);
    a[4] += bfl(v.z); a[5] += bfh(v.z);
    a[6] += bfl(v.w); a[7] += bfh(v.w);
}

__device__ __forceinline__ void gload_lds16(const void* g, void* l) {
    __builtin_amdgcn_global_load_lds(
        (const __attribute__((address_space(1))) unsigned int*)g,
        (__attribute__((address_space(3))) unsigned int*)l, 16, 0, 0);
}

__global__ void zero_i32(int* __restrict__ p, int n) {
    int i = blockIdx.x * blockDim.x + threadIdx.x;
    if (i < n) p[i] = 0;
}

__global__ void count_deg(const int* __restrict__ ei, int* __restrict__ cnt, int E) {
    int e = blockIdx.x * blockDim.x + threadIdx.x;
    if (e < E) atomicAdd(&cnt[ei[E + e]], 1);
}

__global__ void dinv_from_cnt(const int* __restrict__ cnt, float* __restrict__ dinv, int n) {
    int i = blockIdx.x * blockDim.x + threadIdx.x;
    if (i < n) dinv[i] = rsqrtf((float)cnt[i] + 1.0f);   // +1 self-loop
}

#define SCAN_BLK 256
#define SCAN_ELEMS 1024

__global__ void scan_blocks(const int* __restrict__ cnt, int* __restrict__ out,
                            int* __restrict__ bsums, int n) {
    __shared__ int lds[SCAN_BLK];
    int base = blockIdx.x * SCAN_ELEMS;
    int t = threadIdx.x;
    int v[4];
    int s = 0;
#pragma unroll
    for (int j = 0; j < 4; j++) {
        int i = base + t * 4 + j;
        v[j] = s;
        s += (i < n) ? cnt[i] : 0;
    }
    lds[t] = s;
    __syncthreads();
    for (int off = 1; off < SCAN_BLK; off <<= 1) {
        int val = (t >= off) ? lds[t - off] : 0;
        __syncthreads();
        lds[t] += val;
        __syncthreads();
    }
    int excl = (t == 0) ? 0 : lds[t - 1];
#pragma unroll
    for (int j = 0; j < 4; j++) {
        int i = base + t * 4 + j;
        if (i < n) out[i] = excl + v[j];
    }
    if (t == SCAN_BLK - 1) bsums[blockIdx.x] = lds[t];
}

__global__ void scan_bsums(int* __restrict__ bsums, int nb) {
    if (threadIdx.x == 0 && blockIdx.x == 0) {
        int acc = 0;
        for (int i = 0; i < nb; i++) { int c = bsums[i]; bsums[i] = acc; acc += c; }
    }
}

__global__ void scan_add(int* __restrict__ row_ptr, const int* __restrict__ bsums, int n, int E) {
    int i = blockIdx.x * blockDim.x + threadIdx.x;
    if (i < n) row_ptr[i] += bsums[i / SCAN_ELEMS];
    if (i == 0) row_ptr[n] = E;
}

__global__ void fill_edges(const int* __restrict__ ei, const int* __restrict__ row_ptr,
                           int* __restrict__ cnt, int* __restrict__ edge_src, int E) {
    int e = blockIdx.x * blockDim.x + threadIdx.x;
    if (e >= E) return;
    int s = ei[e], d = ei[E + e];
    int off = atomicSub(&cnt[d], 1) - 1;
    edge_src[row_ptr[d] + off] = s;
}

// ---- BN statistics: 4-deep row unroll, non-atomic partials ----------------
__global__ __launch_bounds__(256) void bn_stats(const float4* __restrict__ x4,
                                                float* __restrict__ partials, int n) {
    int t = threadIdx.x;
    int cg = t & 31;          // column group (float4)
    int rs = t >> 5;          // row slice 0..7, 4 rows each
    float4 s = make_float4(0.f, 0.f, 0.f, 0.f);
    float4 q = make_float4(0.f, 0.f, 0.f, 0.f);
    const float4 z4 = make_float4(0.f, 0.f, 0.f, 0.f);
    const int stride = BN_G * 32;
    for (int r0 = blockIdx.x * 32 + rs * 4; r0 < n; r0 += stride) {
        float4 v0 = x4[(size_t)r0 * 32 + cg];
        float4 v1 = (r0 + 1 < n) ? x4[(size_t)(r0 + 1) * 32 + cg] : z4;
        float4 v2 = (r0 + 2 < n) ? x4[(size_t)(r0 + 2) * 32 + cg] : z4;
        float4 v3 = (r0 + 3 < n) ? x4[(size_t)(r0 + 3) * 32 + cg] : z4;
        s.x += v0.x + v1.x + v2.x + v3.x;
        s.y += v0.y + v1.y + v2.y + v3.y;
        s.z += v0.z + v1.z + v2.z + v3.z;
        s.w += v0.w + v1.w + v2.w + v3.w;
        q.x = fmaf(v0.x, v0.x, fmaf(v1.x, v1.x, fmaf(v2.x, v2.x, fmaf(v3.x, v3.x, q.x))));
        q.y = fmaf(v0.y, v0.y, fmaf(v1.y, v1.y, fmaf(v2.y, v2.y, fmaf(v3.y, v3.y, q.y))));
        q.z = fmaf(v0.z, v0.z, fmaf(v1.z, v1.z, fmaf(v2.z, v2.z, fmaf(v3.z, v3.z, q.z))));
        q.w = fmaf(v0.w, v0.w, fmaf(v1.w, v1.w, fmaf(v2.w, v2.w, fmaf(v3.w, v3.w, q.w))));
    }
    __shared__ float4 lds[2][8][32];
    lds[0][rs][cg] = s;
    lds[1][rs][cg] = q;
    __syncthreads();
    if (t < 64) {
        int which = t >> 5;   // 0: sum, 1: sumsq
        int c = t & 31;
        float4 a = lds[which][0][c];
#pragma unroll
        for (int i = 1; i < 8; i++) {
            float4 b = lds[which][i][c];
            a.x += b.x; a.y += b.y; a.z += b.z; a.w += b.w;
        }
        int base = which * 128 + c * 4;
        partials[(size_t)(base + 0) * BN_G + blockIdx.x] = a.x;
        partials[(size_t)(base + 1) * BN_G + blockIdx.x] = a.y;
        partials[(size_t)(base + 2) * BN_G + blockIdx.x] = a.z;
        partials[(size_t)(base + 3) * BN_G + blockIdx.x] = a.w;
    }
}

// one block per output element c in [0,256): stats[c] = sum over BN_G partials
__global__ void bn_reduce(const float4* __restrict__ partials4, float* __restrict__ stats) {
    __shared__ float red[256];
    int c = blockIdx.x, t = threadIdx.x;
    float4 v = partials4[(size_t)c * (BN_G / 4) + t];
    red[t] = v.x + v.y + v.z + v.w;
    __syncthreads();
    for (int off = 128; off > 0; off >>= 1) {
        if (t < off) red[t] += red[t + off];
        __syncthreads();
    }
    if (t == 0) stats[c] = red[0];
}

__global__ void bn_finalize(const float* __restrict__ colsum, const float* __restrict__ colsumsq,
                            const float* __restrict__ gamma, const float* __restrict__ beta,
                            float* __restrict__ scale, float* __restrict__ shift, float invN) {
    int c = threadIdx.x;
    float mu = colsum[c] * invN;
    float var = colsumsq[c] * invN - mu * mu;
    float sc = gamma[c] / sqrtf(var + 1e-5f);
    scale[c] = sc;
    shift[c] = beta[c] - mu * sc;
}

// x -> bn -> bf16 ; noise -> bf16. One pass, float4 in / ushort4 out.
__global__ void convert_inputs(const float4* __restrict__ x4, const float4* __restrict__ n4,
                               const float* __restrict__ scale, const float* __restrict__ shift,
                               ushort4* __restrict__ xb, ushort4* __restrict__ nb, int total4) {
    int i = blockIdx.x * blockDim.x + threadIdx.x;
    if (i >= total4) return;
    int c4 = (i & 31) << 2;
    float4 sc = *reinterpret_cast<const float4*>(scale + c4);
    float4 sh = *reinterpret_cast<const float4*>(shift + c4);
    float4 v = x4[i];
    ushort4 o;
    o.x = f2bf(fmaf(v.x, sc.x, sh.x));
    o.y = f2bf(fmaf(v.y, sc.y, sh.y));
    o.z = f2bf(fmaf(v.z, sc.z, sh.z));
    o.w = f2bf(fmaf(v.w, sc.w, sh.w));
    xb[i] = o;
    float4 w = n4[i];
    ushort4 p;
    p.x = f2bf(w.x); p.y = f2bf(w.y); p.z = f2bf(w.z); p.w = f2bf(w.w);
    nb[i] = p;
}

// ---------------------------------------------------------------------------
// pack W (fp32 [K][C] row-major, writes a column slice [colOff, colOff+C))
// into MFMA fragment layout: region ((s*2+wc)*4+kc)*4+n is 1KB, laid out
// [lane][j]: col = wc*64+n*16+l15, k = s*128+kc*32+lhi*8+j, lane = lhi*16+l15.
// Wave-coalesced 1KB per fragment load in the GEMM.
// ---------------------------------------------------------------------------
__global__ void pack_w(const float* __restrict__ W, unsigned short* __restrict__ Wp,
                       int K, int C, int colOff) {
    int i = blockIdx.x * blockDim.x + threadIdx.x;   // over K*C
    if (i >= K * C) return;
    int k = i / C, c = i % C;
    int gc = c + colOff;
    int s = k >> 7, kc = (k >> 5) & 3, lhi = (k >> 3) & 3, j = k & 7;
    int wc = gc >> 6, n = (gc >> 4) & 3, l15 = gc & 15;
    int lane = lhi * 16 + l15;
    size_t dst = ((size_t)((s * 2 + wc) * 4 + kc) * 4 + n) * 512 + lane * 8 + j;
    Wp[dst] = f2bf(W[i]);
}

// ---------------------------------------------------------------------------
// MFMA GEMM: hs[MP x 128] = (sum_s A_s[MP x 128] @ W[s*128:, :]) * dinv[row]
// Block 64 rows x 128 cols, 4 waves 2x2; wave tile 32 rows x 64 cols.
// A-tile staged to LDS by global_load_lds (swizzled source, linear dest,
// swizzled ds_read). W fragments: packed layout -> 16 coalesced 1KB loads
// per wave per source, preloaded before the barrier (drain with stage(s)).
// ---------------------------------------------------------------------------
template <int NSRC>
__global__ __launch_bounds__(256, 4) void gemm_mfma(
    const unsigned short* __restrict__ A0, const unsigned short* __restrict__ A1,
    const unsigned short* __restrict__ A2,
    const unsigned short* __restrict__ Wpk,  // packed fragments
    const float* __restrict__ dinv, unsigned short* __restrict__ out)
{
    constexpr int NBUF = (NSRC > 1) ? 2 : 1;
    __shared__ unsigned char ldsA[NBUF][64 * 256];   // [rows][128k * 2B]

    const int lane = threadIdx.x & 63;
    const int wid  = threadIdx.x >> 6;
    const int wr   = wid >> 1, wc = wid & 1;
    const int l15  = lane & 15, lhi = lane >> 4;
    const int c0   = wc * 64;
    const long rowblk = (long)blockIdx.x * 64;
    const int rl0 = wr * 32 + l15;      // local rows this lane covers
    const int rl1 = rl0 + 16;
    const int rsw = rl0 & 7;            // same for rl1 (+16)

    // staging: wave wid stages granules G = (wid*4+i)*64 + lane (16B each)
    const unsigned short* __restrict__ srcs[3] = {A0, A1, A2};
    auto stage = [&](int s, int b) {
#pragma unroll
        for (int i = 0; i < 4; i++) {
            int G = (wid * 4 + i) * 64 + lane;   // 0..1023 granules of 16B
            int r = G >> 4, g = G & 15;
            const unsigned short* src = srcs[s] + (rowblk + r) * 128 + (g ^ (r & 7)) * 8;
            gload_lds16(src, &ldsA[b][G * 16]);
        }
    };

    f32x4 acc[2][4];
#pragma unroll
    for (int g = 0; g < 2; g++)
#pragma unroll
        for (int n = 0; n < 4; n++)
            acc[g][n] = (f32x4){0.f, 0.f, 0.f, 0.f};

    stage(0, 0);

#pragma unroll
    for (int s = 0; s < NSRC; s++) {
        // W fragments for source s: 16 wave-coalesced 1KB loads (same address
        // in every block -> L2 broadcast). Issued before the barrier so they
        // drain together with stage(s), hidden under its latency.
        const unsigned short* wbase = Wpk + ((size_t)(s * 2 + wc) * 16) * 512 + lane * 8;
        bf16x8 w[4][4];
#pragma unroll
        for (int kc = 0; kc < 4; kc++)
#pragma unroll
            for (int n = 0; n < 4; n++)
                w[kc][n] = *reinterpret_cast<const bf16x8*>(wbase + (kc * 4 + n) * 512);

        __syncthreads();                         // stage(s) + W(s) complete
        if (s + 1 < NSRC) stage(s + 1, (s + 1) % NBUF);
        const unsigned char* bufp = ldsA[s % NBUF];

#pragma unroll
        for (int kc = 0; kc < 4; kc++) {
            int g0 = kc * 4 + lhi;
            bf16x8 a0 = *reinterpret_cast<const bf16x8*>(bufp + rl0 * 256 + (g0 ^ rsw) * 16);
            bf16x8 a1 = *reinterpret_cast<const bf16x8*>(bufp + rl1 * 256 + (g0 ^ rsw) * 16);
#pragma unroll
            for (int n = 0; n < 4; n++) {
                acc[0][n] = __builtin_amdgcn_mfma_f32_16x16x32_bf16(w[kc][n], a0, acc[0][n], 0, 0, 0);
                acc[1][n] = __builtin_amdgcn_mfma_f32_16x16x32_bf16(w[kc][n], a1, acc[1][n], 0, 0, 0);
            }
        }
    }

#pragma unroll
    for (int g = 0; g < 2; g++) {
        long row = rowblk + (g ? rl1 : rl0);
        float dv = dinv[row];
        unsigned short* op = out + row * 128 + c0 + lhi * 4;
#pragma unroll
        for (int n = 0; n < 4; n++) {
            f32x4 v = acc[g][n];
            ushort4 pk;
            pk.x = f2bf(v[0] * dv);
            pk.y = f2bf(v[1] * dv);
            pk.z = f2bf(v[2] * dv);
            pk.w = f2bf(v[3] * dv);
            *reinterpret_cast<ushort4*>(op + n * 16) = pk;
        }
    }
}

// ---------------------------------------------------------------------------
// CSR gather: one wave per node; 16 lanes x uint4 (16B) cover one 256B row;
// 4 sub-groups stride the edge list; cross-sub shuffle reduce at the end.
// ---------------------------------------------------------------------------
template <bool RELU>
__global__ void gather16(const uint4* __restrict__ hs4, const float* __restrict__ dinv,
                         const int* __restrict__ row_ptr, const int* __restrict__ edge_src,
                         const float* __restrict__ bias, uint4* __restrict__ out4, int n) {
    int node = blockIdx.x * 4 + (threadIdx.x >> 6);
    if (node >= n) return;
    int lane = threadIdx.x & 63;
    int cl = lane & 15, sub = lane >> 4;
    int beg = row_ptr[node], end = row_ptr[node + 1];
    float a0[8] = {0.f,0.f,0.f,0.f,0.f,0.f,0.f,0.f};
    float a1[8] = {0.f,0.f,0.f,0.f,0.f,0.f,0.f,0.f};
    if (sub == 0) acc8(a0, hs4[(size_t)node * 16 + cl]);   // self-loop
    int e = beg + sub;
    for (; e + 4 < end; e += 8) {
        uint4 v0 = hs4[(size_t)edge_src[e] * 16 + cl];
        uint4 v1 = hs4[(size_t)edge_src[e + 4] * 16 + cl];
        acc8(a0, v0);
        acc8(a1, v1);
    }
    if (e < end) acc8(a0, hs4[(size_t)edge_src[e] * 16 + cl]);
#pragma unroll
    for (int i = 0; i < 8; i++) a0[i] += a1[i];
#pragma unroll
    for (int i = 0; i < 8; i++) {
        a0[i] += __shfl_xor(a0[i], 16);
        a0[i] += __shfl_xor(a0[i], 32);
    }
    if (sub == 0) {
        float dv = dinv[node];
        float4 b0 = *reinterpret_cast<const float4*>(bias + cl * 8);
        float4 b1 = *reinterpret_cast<const float4*>(bias + cl * 8 + 4);
        float r0 = fmaf(a0[0], dv, b0.x), r1 = fmaf(a0[1], dv, b0.y);
        float r2 = fmaf(a0[2], dv, b0.z), r3 = fmaf(a0[3], dv, b0.w);
        float r4 = fmaf(a0[4], dv, b1.x), r5 = fmaf(a0[5], dv, b1.y);
        float r6 = fmaf(a0[6], dv, b1.z), r7 = fmaf(a0[7], dv, b1.w);
        if (RELU) {
            r0 = fmaxf(r0, 0.f); r1 = fmaxf(r1, 0.f); r2 = fmaxf(r2, 0.f); r3 = fmaxf(r3, 0.f);
            r4 = fmaxf(r4, 0.f); r5 = fmaxf(r5, 0.f); r6 = fmaxf(r6, 0.f); r7 = fmaxf(r7, 0.f);
        }
        uint4 o;
        o.x = pack2(r0, r1); o.y = pack2(r2, r3);
        o.z = pack2(r4, r5); o.w = pack2(r6, r7);
        out4[(size_t)node * 16 + cl] = o;
    }
}

// final: t rows = [tm(64) | ts(64)] bf16 -> zm, zs fp32
__global__ void gather_dual(const uint4* __restrict__ hs4, const float* __restrict__ dinv,
                            const int* __restrict__ row_ptr, const int* __restrict__ edge_src,
                            const float* __restrict__ bm, const float* __restrict__ bs,
                            float* __restrict__ zm, float* __restrict__ zs, int n) {
    int node = blockIdx.x * 4 + (threadIdx.x >> 6);
    if (node >= n) return;
    int lane = threadIdx.x & 63;
    int cl = lane & 15, sub = lane >> 4;
    int beg = row_ptr[node], end = row_ptr[node + 1];
    float a0[8] = {0.f,0.f,0.f,0.f,0.f,0.f,0.f,0.f};
    float a1[8] = {0.f,0.f,0.f,0.f,0.f,0.f,0.f,0.f};
    if (sub == 0) acc8(a0, hs4[(size_t)node * 16 + cl]);
    int e = beg + sub;
    for (; e + 4 < end; e += 8) {
        uint4 v0 = hs4[(size_t)edge_src[e] * 16 + cl];
        uint4 v1 = hs4[(size_t)edge_src[e + 4] * 16 + cl];
        acc8(a0, v0);
        acc8(a1, v1);
    }
    if (e < end) acc8(a0, hs4[(size_t)edge_src[e] * 16 + cl]);
#pragma unroll
    for (int i = 0; i < 8; i++) a0[i] += a1[i];
#pragma unroll
    for (int i = 0; i < 8; i++) {
        a0[i] += __shfl_xor(a0[i], 16);
        a0[i] += __shfl_xor(a0[i], 32);
    }
    if (sub == 0) {
        float dv = dinv[node];
        const float* bp = (cl < 8) ? (bm + cl * 8) : (bs + (cl - 8) * 8);
        float* zp = (cl < 8) ? (zm + (size_t)node * 64 + cl * 8)
                             : (zs + (size_t)node * 64 + (cl - 8) * 8);
        float4 b0 = *reinterpret_cast<const float4*>(bp);
        float4 b1 = *reinterpret_cast<const float4*>(bp + 4);
        float4 o0 = make_float4(fmaf(a0[0], dv, b0.x), fmaf(a0[1], dv, b0.y),
                                fmaf(a0[2], dv, b0.z), fmaf(a0[3], dv, b0.w));
        float4 o1 = make_float4(fmaf(a0[4], dv, b1.x), fmaf(a0[5], dv, b1.y),
                                fmaf(a0[6], dv, b1.z), fmaf(a0[7], dv, b1.w));
        *reinterpret_cast<float4*>(zp) = o0;
        *reinterpret_cast<float4*>(zp + 4) = o1;
    }
}

// ---------------------------------------------------------------------------

extern "C" void kernel_launch(void* const* d_in, const int* in_sizes, int n_in,
                              void* d_out, int out_size, void* d_ws, size_t ws_size,
                              hipStream_t stream) {
    const float* x     = (const float*)d_in[0];
    const float* noise = (const float*)d_in[1];
    const int*   ei    = (const int*)d_in[2];
    const float* gamma = (const float*)d_in[3];
    const float* beta  = (const float*)d_in[4];
    const float* W1    = (const float*)d_in[5];
    const float* b1    = (const float*)d_in[6];
    const float* W2    = (const float*)d_in[7];
    const float* b2    = (const float*)d_in[8];
    const float* Wm    = (const float*)d_in[9];
    const float* bm    = (const float*)d_in[10];
    const float* Ws    = (const float*)d_in[11];
    const float* bs    = (const float*)d_in[12];

    const int N  = in_sizes[0] / 128;
    const int E  = in_sizes[2] / 2;
    const int NPAD = (N + 127) & ~127;        // row-padded size for GEMM buffers
    const int nb = (N + SCAN_ELEMS - 1) / SCAN_ELEMS;

    auto align256 = [](size_t b) { return (b + 255) & ~(size_t)255; };
    char* p = (char*)d_ws;
    int* cnt      = (int*)p;  p += align256((size_t)N * 4);
    int* row_ptr  = (int*)p;  p += align256((size_t)(N + 1) * 4);
    int* edge_src = (int*)p;  p += align256((size_t)E * 4);
    int* bsums    = (int*)p;  p += align256((size_t)nb * 4);
    float* dinv   = (float*)p; p += align256((size_t)NPAD * 4);
    float* stats  = (float*)p; p += align256(512 * 4);
    float* bnpart = (float*)p; p += align256((size_t)256 * BN_G * 4);
    unsigned short* Wp1 = (unsigned short*)p; p += align256(128 * 128 * 2);
    unsigned short* Wp2 = (unsigned short*)p; p += align256(128 * 384 * 2);
    unsigned short* Wpc = (unsigned short*)p; p += align256(128 * 256 * 2);
    unsigned short* xb16 = (unsigned short*)p; p += align256((size_t)NPAD * 128 * 2);
    unsigned short* n16  = (unsigned short*)p; p += align256((size_t)NPAD * 128 * 2);  // noise, then hs3
    unsigned short* h16  = (unsigned short*)p; p += align256((size_t)NPAD * 128 * 2);  // h1, then h2

    float* colsum   = stats;
    float* colsumsq = stats + 128;
    float* scale    = stats + 256;
    float* shift    = stats + 384;

    float* dout = (float*)d_out;                       // N*128 fp32
    unsigned short* hs12 = (unsigned short*)d_out;     // conv1/2 hs scratch (bf16, NPAD rows fit)
    unsigned short* hs3  = n16;                        // noise dead after conv2
    float* zm = dout;                                  // [N*64]
    float* zs = dout + (size_t)N * 64;                 // [N*64]

    const int gblocks = NPAD / 64;
    const int nblocks4 = (N + 3) / 4;

    // --- graph structure + BN stats + conversions ---
    zero_i32<<<(N + 255) / 256, 256, 0, stream>>>(cnt, N);
    count_deg<<<(E + 255) / 256, 256, 0, stream>>>(ei, cnt, E);
    bn_stats<<<BN_G, 256, 0, stream>>>((const float4*)x, bnpart, N);
    bn_reduce<<<256, 256, 0, stream>>>((const float4*)bnpart, stats);
    bn_finalize<<<1, 128, 0, stream>>>(colsum, colsumsq, gamma, beta, scale, shift, 1.0f / (float)N);
    scan_blocks<<<nb, SCAN_BLK, 0, stream>>>(cnt, row_ptr, bsums, N);
    scan_bsums<<<1, 64, 0, stream>>>(bsums, nb);
    scan_add<<<(N + 255) / 256, 256, 0, stream>>>(row_ptr, bsums, N, E);
    dinv_from_cnt<<<(N + 255) / 256, 256, 0, stream>>>(cnt, dinv, N);
    fill_edges<<<(E + 255) / 256, 256, 0, stream>>>(ei, row_ptr, cnt, edge_src, E);
    convert_inputs<<<(N * 32 + 255) / 256, 256, 0, stream>>>(
        (const float4*)x, (const float4*)noise, scale, shift,
        (ushort4*)xb16, (ushort4*)n16, N * 32);
    pack_w<<<(128 * 128 + 255) / 256, 256, 0, stream>>>(W1, Wp1, 128, 128, 0);
    pack_w<<<(384 * 128 + 255) / 256, 256, 0, stream>>>(W2, Wp2, 384, 128, 0);
    pack_w<<<(256 * 64 + 255) / 256, 256, 0, stream>>>(Wm, Wpc, 256, 64, 0);
    pack_w<<<(256 * 64 + 255) / 256, 256, 0, stream>>>(Ws, Wpc, 256, 64, 64);

    // conv1
    gemm_mfma<1><<<gblocks, 256, 0, stream>>>(xb16, nullptr, nullptr, Wp1, dinv, hs12);
    gather16<true><<<nblocks4, 256, 0, stream>>>((const uint4*)hs12, dinv, row_ptr,
                                                 edge_src, b1, (uint4*)h16, N);
    // conv2
    gemm_mfma<3><<<gblocks, 256, 0, stream>>>(xb16, n16, h16, Wp2, dinv, hs12);
    gather16<true><<<nblocks4, 256, 0, stream>>>((const uint4*)hs12, dinv, row_ptr,
                                                 edge_src, b2, (uint4*)h16, N);
    // mean/logstd fused (hs -> n16 slot; d_out now gets final fp32 outputs)
    gemm_mfma<2><<<gblocks, 256, 0, stream>>>(xb16, h16, nullptr, Wpc, dinv, hs3);
    gather_dual<<<nblocks4, 256, 0, stream>>>((const uint4*)hs3, dinv, row_ptr,
                                              edge_src, bm, bs, zm, zs, N);
}

// Round 11
// 317.879 us; speedup vs baseline: 1.3190x; 1.1120x over previous
//
#include <hip/hip_runtime.h>
#include <math.h>

// ---------------------------------------------------------------------------
// GCN encoder forward, bf16 MFMA formulation:
//   CSR build: count_deg stores per-edge slot (atomic return) -> scan ->
//   fill_edges is ATOMIC-FREE (edge_src[row_ptr[d]+slot[e]] = s)
//   BN stats (fp32, partials + reduce); xb16 = bn(x) bf16; noise16 = bf16
//   W pre-packed into MFMA-fragment layout (contiguous 1KB per fragment)
//   hs16 = (concat srcs @ W) * dinv[row]   (MFMA gemm, bf16 out)
//   out[d] = act(dinv[d]*(sum_in hs16[src] + hs16[d]) + bias)  (CSR gather)
// ---------------------------------------------------------------------------

typedef short bf16x8 __attribute__((ext_vector_type(8)));
typedef float f32x4 __attribute__((ext_vector_type(4)));

#define BN_G 1024

__device__ inline unsigned short f2bf(float f) {  // RNE
    unsigned int u = __builtin_bit_cast(unsigned int, f);
    u += 0x7fff + ((u >> 16) & 1);
    return (unsigned short)(u >> 16);
}
__device__ inline float bfl(unsigned int u) { return __builtin_bit_cast(float, u << 16); }
__device__ inline float bfh(unsigned int u) { return __builtin_bit_cast(float, u & 0xffff0000u); }
__device__ inline unsigned int pack2(float lo, float hi) {
    return ((unsigned int)f2bf(hi) << 16) | f2bf(lo);
}
__device__ inline void acc8(float* a, uint4 v) {
    a[0] += bfl(v.x); a[1] += bfh(v.x);
    a[2] += bfl(v.y); a[3] += bfh(v.y);
    a[4] += bfl(v.z); a[5] += bfh(v.z);
    a[6] += bfl(v.w); a[7] += bfh(v.w);
}

__device__ __forceinline__ void gload_lds16(const void* g, void* l) {
    __builtin_amdgcn_global_load_lds(
        (const __attribute__((address_space(1))) unsigned int*)g,
        (__attribute__((address_space(3))) unsigned int*)l, 16, 0, 0);
}

__global__ void zero_i32(int* __restrict__ p, int n) {
    int i = blockIdx.x * blockDim.x + threadIdx.x;
    if (i < n) p[i] = 0;
}

// count in-degree AND record each edge's slot within its dst bucket
__global__ void count_deg(const int* __restrict__ ei, int* __restrict__ cnt,
                          int* __restrict__ slot, int E) {
    int e = blockIdx.x * blockDim.x + threadIdx.x;
    if (e < E) slot[e] = atomicAdd(&cnt[ei[E + e]], 1);
}

__global__ void dinv_from_cnt(const int* __restrict__ cnt, float* __restrict__ dinv, int n) {
    int i = blockIdx.x * blockDim.x + threadIdx.x;
    if (i < n) dinv[i] = rsqrtf((float)cnt[i] + 1.0f);   // +1 self-loop
}

#define SCAN_BLK 256
#define SCAN_ELEMS 1024

__global__ void scan_blocks(const int* __restrict__ cnt, int* __restrict__ out,
                            int* __restrict__ bsums, int n) {
    __shared__ int lds[SCAN_BLK];
    int base = blockIdx.x * SCAN_ELEMS;
    int t = threadIdx.x;
    int v[4];
    int s = 0;
#pragma unroll
    for (int j = 0; j < 4; j++) {
        int i = base + t * 4 + j;
        v[j] = s;
        s += (i < n) ? cnt[i] : 0;
    }
    lds[t] = s;
    __syncthreads();
    for (int off = 1; off < SCAN_BLK; off <<= 1) {
        int val = (t >= off) ? lds[t - off] : 0;
        __syncthreads();
        lds[t] += val;
        __syncthreads();
    }
    int excl = (t == 0) ? 0 : lds[t - 1];
#pragma unroll
    for (int j = 0; j < 4; j++) {
        int i = base + t * 4 + j;
        if (i < n) out[i] = excl + v[j];
    }
    if (t == SCAN_BLK - 1) bsums[blockIdx.x] = lds[t];
}

__global__ void scan_bsums(int* __restrict__ bsums, int nb) {
    if (threadIdx.x == 0 && blockIdx.x == 0) {
        int acc = 0;
        for (int i = 0; i < nb; i++) { int c = bsums[i]; bsums[i] = acc; acc += c; }
    }
}

__global__ void scan_add(int* __restrict__ row_ptr, const int* __restrict__ bsums, int n, int E) {
    int i = blockIdx.x * blockDim.x + threadIdx.x;
    if (i < n) row_ptr[i] += bsums[i / SCAN_ELEMS];
    if (i == 0) row_ptr[n] = E;
}

// atomic-free bucket fill: slot was recorded by count_deg
__global__ void fill_edges(const int* __restrict__ ei, const int* __restrict__ row_ptr,
                           const int* __restrict__ slot, int* __restrict__ edge_src, int E) {
    int e = blockIdx.x * blockDim.x + threadIdx.x;
    if (e >= E) return;
    int s = ei[e], d = ei[E + e];
    edge_src[row_ptr[d] + slot[e]] = s;
}

// ---- BN statistics: 4-deep row unroll, non-atomic partials ----------------
__global__ __launch_bounds__(256) void bn_stats(const float4* __restrict__ x4,
                                                float* __restrict__ partials, int n) {
    int t = threadIdx.x;
    int cg = t & 31;          // column group (float4)
    int rs = t >> 5;          // row slice 0..7, 4 rows each
    float4 s = make_float4(0.f, 0.f, 0.f, 0.f);
    float4 q = make_float4(0.f, 0.f, 0.f, 0.f);
    const float4 z4 = make_float4(0.f, 0.f, 0.f, 0.f);
    const int stride = BN_G * 32;
    for (int r0 = blockIdx.x * 32 + rs * 4; r0 < n; r0 += stride) {
        float4 v0 = x4[(size_t)r0 * 32 + cg];
        float4 v1 = (r0 + 1 < n) ? x4[(size_t)(r0 + 1) * 32 + cg] : z4;
        float4 v2 = (r0 + 2 < n) ? x4[(size_t)(r0 + 2) * 32 + cg] : z4;
        float4 v3 = (r0 + 3 < n) ? x4[(size_t)(r0 + 3) * 32 + cg] : z4;
        s.x += v0.x + v1.x + v2.x + v3.x;
        s.y += v0.y + v1.y + v2.y + v3.y;
        s.z += v0.z + v1.z + v2.z + v3.z;
        s.w += v0.w + v1.w + v2.w + v3.w;
        q.x = fmaf(v0.x, v0.x, fmaf(v1.x, v1.x, fmaf(v2.x, v2.x, fmaf(v3.x, v3.x, q.x))));
        q.y = fmaf(v0.y, v0.y, fmaf(v1.y, v1.y, fmaf(v2.y, v2.y, fmaf(v3.y, v3.y, q.y))));
        q.z = fmaf(v0.z, v0.z, fmaf(v1.z, v1.z, fmaf(v2.z, v2.z, fmaf(v3.z, v3.z, q.z))));
        q.w = fmaf(v0.w, v0.w, fmaf(v1.w, v1.w, fmaf(v2.w, v2.w, fmaf(v3.w, v3.w, q.w))));
    }
    __shared__ float4 lds[2][8][32];
    lds[0][rs][cg] = s;
    lds[1][rs][cg] = q;
    __syncthreads();
    if (t < 64) {
        int which = t >> 5;   // 0: sum, 1: sumsq
        int c = t & 31;
        float4 a = lds[which][0][c];
#pragma unroll
        for (int i = 1; i < 8; i++) {
            float4 b = lds[which][i][c];
            a.x += b.x; a.y += b.y; a.z += b.z; a.w += b.w;
        }
        int base = which * 128 + c * 4;
        partials[(size_t)(base + 0) * BN_G + blockIdx.x] = a.x;
        partials[(size_t)(base + 1) * BN_G + blockIdx.x] = a.y;
        partials[(size_t)(base + 2) * BN_G + blockIdx.x] = a.z;
        partials[(size_t)(base + 3) * BN_G + blockIdx.x] = a.w;
    }
}

// one block per output element c in [0,256): stats[c] = sum over BN_G partials
__global__ void bn_reduce(const float4* __restrict__ partials4, float* __restrict__ stats) {
    __shared__ float red[256];
    int c = blockIdx.x, t = threadIdx.x;
    float4 v = partials4[(size_t)c * (BN_G / 4) + t];
    red[t] = v.x + v.y + v.z + v.w;
    __syncthreads();
    for (int off = 128; off > 0; off >>= 1) {
        if (t < off) red[t] += red[t + off];
        __syncthreads();
    }
    if (t == 0) stats[c] = red[0];
}

__global__ void bn_finalize(const float* __restrict__ colsum, const float* __restrict__ colsumsq,
                            const float* __restrict__ gamma, const float* __restrict__ beta,
                            float* __restrict__ scale, float* __restrict__ shift, float invN) {
    int c = threadIdx.x;
    float mu = colsum[c] * invN;
    float var = colsumsq[c] * invN - mu * mu;
    float sc = gamma[c] / sqrtf(var + 1e-5f);
    scale[c] = sc;
    shift[c] = beta[c] - mu * sc;
}

// x -> bn -> bf16 ; noise -> bf16. One pass, float4 in / ushort4 out.
__global__ void convert_inputs(const float4* __restrict__ x4, const float4* __restrict__ n4,
                               const float* __restrict__ scale, const float* __restrict__ shift,
                               ushort4* __restrict__ xb, ushort4* __restrict__ nb, int total4) {
    int i = blockIdx.x * blockDim.x + threadIdx.x;
    if (i >= total4) return;
    int c4 = (i & 31) << 2;
    float4 sc = *reinterpret_cast<const float4*>(scale + c4);
    float4 sh = *reinterpret_cast<const float4*>(shift + c4);
    float4 v = x4[i];
    ushort4 o;
    o.x = f2bf(fmaf(v.x, sc.x, sh.x));
    o.y = f2bf(fmaf(v.y, sc.y, sh.y));
    o.z = f2bf(fmaf(v.z, sc.z, sh.z));
    o.w = f2bf(fmaf(v.w, sc.w, sh.w));
    xb[i] = o;
    float4 w = n4[i];
    ushort4 p;
    p.x = f2bf(w.x); p.y = f2bf(w.y); p.z = f2bf(w.z); p.w = f2bf(w.w);
    nb[i] = p;
}

// ---------------------------------------------------------------------------
// pack W (fp32 [K][C] row-major, writes a column slice [colOff, colOff+C))
// into MFMA fragment layout: region ((s*2+wc)*4+kc)*4+n is 1KB, laid out
// [lane][j]: col = wc*64+n*16+l15, k = s*128+kc*32+lhi*8+j, lane = lhi*16+l15.
// ---------------------------------------------------------------------------
__global__ void pack_w(const float* __restrict__ W, unsigned short* __restrict__ Wp,
                       int K, int C, int colOff) {
    int i = blockIdx.x * blockDim.x + threadIdx.x;   // over K*C
    if (i >= K * C) return;
    int k = i / C, c = i % C;
    int gc = c + colOff;
    int s = k >> 7, kc = (k >> 5) & 3, lhi = (k >> 3) & 3, j = k & 7;
    int wc = gc >> 6, n = (gc >> 4) & 3, l15 = gc & 15;
    int lane = lhi * 16 + l15;
    size_t dst = ((size_t)((s * 2 + wc) * 4 + kc) * 4 + n) * 512 + lane * 8 + j;
    Wp[dst] = f2bf(W[i]);
}

// ---------------------------------------------------------------------------
// MFMA GEMM: hs[MP x 128] = (sum_s A_s[MP x 128] @ W[s*128:, :]) * dinv[row]
// Block 64 rows x 128 cols, 4 waves 2x2; wave tile 32 rows x 64 cols.
// A-tile staged to LDS by global_load_lds (swizzled source, linear dest,
// swizzled ds_read). W fragments: packed layout -> 16 coalesced 1KB loads
// per wave per source, preloaded before the barrier (drain with stage(s)).
// ---------------------------------------------------------------------------
template <int NSRC>
__global__ __launch_bounds__(256, 4) void gemm_mfma(
    const unsigned short* __restrict__ A0, const unsigned short* __restrict__ A1,
    const unsigned short* __restrict__ A2,
    const unsigned short* __restrict__ Wpk,  // packed fragments
    const float* __restrict__ dinv, unsigned short* __restrict__ out)
{
    constexpr int NBUF = (NSRC > 1) ? 2 : 1;
    __shared__ unsigned char ldsA[NBUF][64 * 256];   // [rows][128k * 2B]

    const int lane = threadIdx.x & 63;
    const int wid  = threadIdx.x >> 6;
    const int wr   = wid >> 1, wc = wid & 1;
    const int l15  = lane & 15, lhi = lane >> 4;
    const int c0   = wc * 64;
    const long rowblk = (long)blockIdx.x * 64;
    const int rl0 = wr * 32 + l15;      // local rows this lane covers
    const int rl1 = rl0 + 16;
    const int rsw = rl0 & 7;            // same for rl1 (+16)

    // staging: wave wid stages granules G = (wid*4+i)*64 + lane (16B each)
    const unsigned short* __restrict__ srcs[3] = {A0, A1, A2};
    auto stage = [&](int s, int b) {
#pragma unroll
        for (int i = 0; i < 4; i++) {
            int G = (wid * 4 + i) * 64 + lane;   // 0..1023 granules of 16B
            int r = G >> 4, g = G & 15;
            const unsigned short* src = srcs[s] + (rowblk + r) * 128 + (g ^ (r & 7)) * 8;
            gload_lds16(src, &ldsA[b][G * 16]);
        }
    };

    f32x4 acc[2][4];
#pragma unroll
    for (int g = 0; g < 2; g++)
#pragma unroll
        for (int n = 0; n < 4; n++)
            acc[g][n] = (f32x4){0.f, 0.f, 0.f, 0.f};

    stage(0, 0);

#pragma unroll
    for (int s = 0; s < NSRC; s++) {
        // W fragments for source s: 16 wave-coalesced 1KB loads (same address
        // in every block -> L2 broadcast), issued before the barrier so they
        // drain together with stage(s).
        const unsigned short* wbase = Wpk + ((size_t)(s * 2 + wc) * 16) * 512 + lane * 8;
        bf16x8 w[4][4];
#pragma unroll
        for (int kc = 0; kc < 4; kc++)
#pragma unroll
            for (int n = 0; n < 4; n++)
                w[kc][n] = *reinterpret_cast<const bf16x8*>(wbase + (kc * 4 + n) * 512);

        __syncthreads();                         // stage(s) + W(s) complete
        if (s + 1 < NSRC) stage(s + 1, (s + 1) % NBUF);
        const unsigned char* bufp = ldsA[s % NBUF];

#pragma unroll
        for (int kc = 0; kc < 4; kc++) {
            int g0 = kc * 4 + lhi;
            bf16x8 a0 = *reinterpret_cast<const bf16x8*>(bufp + rl0 * 256 + (g0 ^ rsw) * 16);
            bf16x8 a1 = *reinterpret_cast<const bf16x8*>(bufp + rl1 * 256 + (g0 ^ rsw) * 16);
#pragma unroll
            for (int n = 0; n < 4; n++) {
                acc[0][n] = __builtin_amdgcn_mfma_f32_16x16x32_bf16(w[kc][n], a0, acc[0][n], 0, 0, 0);
                acc[1][n] = __builtin_amdgcn_mfma_f32_16x16x32_bf16(w[kc][n], a1, acc[1][n], 0, 0, 0);
            }
        }
    }

#pragma unroll
    for (int g = 0; g < 2; g++) {
        long row = rowblk + (g ? rl1 : rl0);
        float dv = dinv[row];
        unsigned short* op = out + row * 128 + c0 + lhi * 4;
#pragma unroll
        for (int n = 0; n < 4; n++) {
            f32x4 v = acc[g][n];
            ushort4 pk;
            pk.x = f2bf(v[0] * dv);
            pk.y = f2bf(v[1] * dv);
            pk.z = f2bf(v[2] * dv);
            pk.w = f2bf(v[3] * dv);
            *reinterpret_cast<ushort4*>(op + n * 16) = pk;
        }
    }
}

// ---------------------------------------------------------------------------
// CSR gather: one wave per node; 16 lanes x uint4 (16B) cover one 256B row;
// 4 sub-groups stride the edge list; cross-sub shuffle reduce at the end.
// ---------------------------------------------------------------------------
template <bool RELU>
__global__ void gather16(const uint4* __restrict__ hs4, const float* __restrict__ dinv,
                         const int* __restrict__ row_ptr, const int* __restrict__ edge_src,
                         const float* __restrict__ bias, uint4* __restrict__ out4, int n) {
    int node = blockIdx.x * 4 + (threadIdx.x >> 6);
    if (node >= n) return;
    int lane = threadIdx.x & 63;
    int cl = lane & 15, sub = lane >> 4;
    int beg = row_ptr[node], end = row_ptr[node + 1];
    float a0[8] = {0.f,0.f,0.f,0.f,0.f,0.f,0.f,0.f};
    float a1[8] = {0.f,0.f,0.f,0.f,0.f,0.f,0.f,0.f};
    if (sub == 0) acc8(a0, hs4[(size_t)node * 16 + cl]);   // self-loop
    int e = beg + sub;
    for (; e + 4 < end; e += 8) {
        uint4 v0 = hs4[(size_t)edge_src[e] * 16 + cl];
        uint4 v1 = hs4[(size_t)edge_src[e + 4] * 16 + cl];
        acc8(a0, v0);
        acc8(a1, v1);
    }
    if (e < end) acc8(a0, hs4[(size_t)edge_src[e] * 16 + cl]);
#pragma unroll
    for (int i = 0; i < 8; i++) a0[i] += a1[i];
#pragma unroll
    for (int i = 0; i < 8; i++) {
        a0[i] += __shfl_xor(a0[i], 16);
        a0[i] += __shfl_xor(a0[i], 32);
    }
    if (sub == 0) {
        float dv = dinv[node];
        float4 b0 = *reinterpret_cast<const float4*>(bias + cl * 8);
        float4 b1 = *reinterpret_cast<const float4*>(bias + cl * 8 + 4);
        float r0 = fmaf(a0[0], dv, b0.x), r1 = fmaf(a0[1], dv, b0.y);
        float r2 = fmaf(a0[2], dv, b0.z), r3 = fmaf(a0[3], dv, b0.w);
        float r4 = fmaf(a0[4], dv, b1.x), r5 = fmaf(a0[5], dv, b1.y);
        float r6 = fmaf(a0[6], dv, b1.z), r7 = fmaf(a0[7], dv, b1.w);
        if (RELU) {
            r0 = fmaxf(r0, 0.f); r1 = fmaxf(r1, 0.f); r2 = fmaxf(r2, 0.f); r3 = fmaxf(r3, 0.f);
            r4 = fmaxf(r4, 0.f); r5 = fmaxf(r5, 0.f); r6 = fmaxf(r6, 0.f); r7 = fmaxf(r7, 0.f);
        }
        uint4 o;
        o.x = pack2(r0, r1); o.y = pack2(r2, r3);
        o.z = pack2(r4, r5); o.w = pack2(r6, r7);
        out4[(size_t)node * 16 + cl] = o;
    }
}

// final: t rows = [tm(64) | ts(64)] bf16 -> zm, zs fp32
__global__ void gather_dual(const uint4* __restrict__ hs4, const float* __restrict__ dinv,
                            const int* __restrict__ row_ptr, const int* __restrict__ edge_src,
                            const float* __restrict__ bm, const float* __restrict__ bs,
                            float* __restrict__ zm, float* __restrict__ zs, int n) {
    int node = blockIdx.x * 4 + (threadIdx.x >> 6);
    if (node >= n) return;
    int lane = threadIdx.x & 63;
    int cl = lane & 15, sub = lane >> 4;
    int beg = row_ptr[node], end = row_ptr[node + 1];
    float a0[8] = {0.f,0.f,0.f,0.f,0.f,0.f,0.f,0.f};
    float a1[8] = {0.f,0.f,0.f,0.f,0.f,0.f,0.f,0.f};
    if (sub == 0) acc8(a0, hs4[(size_t)node * 16 + cl]);
    int e = beg + sub;
    for (; e + 4 < end; e += 8) {
        uint4 v0 = hs4[(size_t)edge_src[e] * 16 + cl];
        uint4 v1 = hs4[(size_t)edge_src[e + 4] * 16 + cl];
        acc8(a0, v0);
        acc8(a1, v1);
    }
    if (e < end) acc8(a0, hs4[(size_t)edge_src[e] * 16 + cl]);
#pragma unroll
    for (int i = 0; i < 8; i++) a0[i] += a1[i];
#pragma unroll
    for (int i = 0; i < 8; i++) {
        a0[i] += __shfl_xor(a0[i], 16);
        a0[i] += __shfl_xor(a0[i], 32);
    }
    if (sub == 0) {
        float dv = dinv[node];
        const float* bp = (cl < 8) ? (bm + cl * 8) : (bs + (cl - 8) * 8);
        float* zp = (cl < 8) ? (zm + (size_t)node * 64 + cl * 8)
                             : (zs + (size_t)node * 64 + (cl - 8) * 8);
        float4 b0 = *reinterpret_cast<const float4*>(bp);
        float4 b1 = *reinterpret_cast<const float4*>(bp + 4);
        float4 o0 = make_float4(fmaf(a0[0], dv, b0.x), fmaf(a0[1], dv, b0.y),
                                fmaf(a0[2], dv, b0.z), fmaf(a0[3], dv, b0.w));
        float4 o1 = make_float4(fmaf(a0[4], dv, b1.x), fmaf(a0[5], dv, b1.y),
                                fmaf(a0[6], dv, b1.z), fmaf(a0[7], dv, b1.w));
        *reinterpret_cast<float4*>(zp) = o0;
        *reinterpret_cast<float4*>(zp + 4) = o1;
    }
}

// ---------------------------------------------------------------------------

extern "C" void kernel_launch(void* const* d_in, const int* in_sizes, int n_in,
                              void* d_out, int out_size, void* d_ws, size_t ws_size,
                              hipStream_t stream) {
    const float* x     = (const float*)d_in[0];
    const float* noise = (const float*)d_in[1];
    const int*   ei    = (const int*)d_in[2];
    const float* gamma = (const float*)d_in[3];
    const float* beta  = (const float*)d_in[4];
    const float* W1    = (const float*)d_in[5];
    const float* b1    = (const float*)d_in[6];
    const float* W2    = (const float*)d_in[7];
    const float* b2    = (const float*)d_in[8];
    const float* Wm    = (const float*)d_in[9];
    const float* bm    = (const float*)d_in[10];
    const float* Ws    = (const float*)d_in[11];
    const float* bs    = (const float*)d_in[12];

    const int N  = in_sizes[0] / 128;
    const int E  = in_sizes[2] / 2;
    const int NPAD = (N + 127) & ~127;        // row-padded size for GEMM buffers
    const int nb = (N + SCAN_ELEMS - 1) / SCAN_ELEMS;

    auto align256 = [](size_t b) { return (b + 255) & ~(size_t)255; };
    char* p = (char*)d_ws;
    int* cnt      = (int*)p;  p += align256((size_t)N * 4);
    int* row_ptr  = (int*)p;  p += align256((size_t)(N + 1) * 4);
    int* edge_src = (int*)p;  p += align256((size_t)E * 4);
    int* slot     = (int*)p;  p += align256((size_t)E * 4);
    int* bsums    = (int*)p;  p += align256((size_t)nb * 4);
    float* dinv   = (float*)p; p += align256((size_t)NPAD * 4);
    float* stats  = (float*)p; p += align256(512 * 4);
    float* bnpart = (float*)p; p += align256((size_t)256 * BN_G * 4);
    unsigned short* Wp1 = (unsigned short*)p; p += align256(128 * 128 * 2);
    unsigned short* Wp2 = (unsigned short*)p; p += align256(128 * 384 * 2);
    unsigned short* Wpc = (unsigned short*)p; p += align256(128 * 256 * 2);
    unsigned short* xb16 = (unsigned short*)p; p += align256((size_t)NPAD * 128 * 2);
    unsigned short* n16  = (unsigned short*)p; p += align256((size_t)NPAD * 128 * 2);  // noise, then hs3
    unsigned short* h16  = (unsigned short*)p; p += align256((size_t)NPAD * 128 * 2);  // h1, then h2

    float* colsum   = stats;
    float* colsumsq = stats + 128;
    float* scale    = stats + 256;
    float* shift    = stats + 384;

    float* dout = (float*)d_out;                       // N*128 fp32
    unsigned short* hs12 = (unsigned short*)d_out;     // conv1/2 hs scratch (bf16, NPAD rows fit)
    unsigned short* hs3  = n16;                        // noise dead after conv2
    float* zm = dout;                                  // [N*64]
    float* zs = dout + (size_t)N * 64;                 // [N*64]

    const int gblocks = NPAD / 64;
    const int nblocks4 = (N + 3) / 4;

    // --- graph structure + BN stats + conversions ---
    zero_i32<<<(N + 255) / 256, 256, 0, stream>>>(cnt, N);
    count_deg<<<(E + 255) / 256, 256, 0, stream>>>(ei, cnt, slot, E);
    bn_stats<<<BN_G, 256, 0, stream>>>((const float4*)x, bnpart, N);
    bn_reduce<<<256, 256, 0, stream>>>((const float4*)bnpart, stats);
    bn_finalize<<<1, 128, 0, stream>>>(colsum, colsumsq, gamma, beta, scale, shift, 1.0f / (float)N);
    scan_blocks<<<nb, SCAN_BLK, 0, stream>>>(cnt, row_ptr, bsums, N);
    scan_bsums<<<1, 64, 0, stream>>>(bsums, nb);
    scan_add<<<(N + 255) / 256, 256, 0, stream>>>(row_ptr, bsums, N, E);
    dinv_from_cnt<<<(N + 255) / 256, 256, 0, stream>>>(cnt, dinv, N);
    fill_edges<<<(E + 255) / 256, 256, 0, stream>>>(ei, row_ptr, slot, edge_src, E);
    convert_inputs<<<(N * 32 + 255) / 256, 256, 0, stream>>>(
        (const float4*)x, (const float4*)noise, scale, shift,
        (ushort4*)xb16, (ushort4*)n16, N * 32);
    pack_w<<<(128 * 128 + 255) / 256, 256, 0, stream>>>(W1, Wp1, 128, 128, 0);
    pack_w<<<(384 * 128 + 255) / 256, 256, 0, stream>>>(W2, Wp2, 384, 128, 0);
    pack_w<<<(256 * 64 + 255) / 256, 256, 0, stream>>>(Wm, Wpc, 256, 64, 0);
    pack_w<<<(256 * 64 + 255) / 256, 256, 0, stream>>>(Ws, Wpc, 256, 64, 64);

    // conv1
    gemm_mfma<1><<<gblocks, 256, 0, stream>>>(xb16, nullptr, nullptr, Wp1, dinv, hs12);
    gather16<true><<<nblocks4, 256, 0, stream>>>((const uint4*)hs12, dinv, row_ptr,
                                                 edge_src, b1, (uint4*)h16, N);
    // conv2
    gemm_mfma<3><<<gblocks, 256, 0, stream>>>(xb16, n16, h16, Wp2, dinv, hs12);
    gather16<true><<<nblocks4, 256, 0, stream>>>((const uint4*)hs12, dinv, row_ptr,
                                                 edge_src, b2, (uint4*)h16, N);
    // mean/logstd fused (hs -> n16 slot; d_out now gets final fp32 outputs)
    gemm_mfma<2><<<gblocks, 256, 0, stream>>>(xb16, h16, nullptr, Wpc, dinv, hs3);
    gather_dual<<<nblocks4, 256, 0, stream>>>((const uint4*)hs3, dinv, row_ptr,
                                              edge_src, bm, bs, zm, zs, N);
}

// Round 12
// 296.042 us; speedup vs baseline: 1.4162x; 1.0738x over previous
//
#include <hip/hip_runtime.h>
#include <math.h>

// ---------------------------------------------------------------------------
// GCN encoder forward, bf16 MFMA formulation.
// Setup DAG fused into 5 mega-kernels (independent chains co-execute):
//   memset(cnt) ; fused1 = bn_stats || count_deg(slot)
//   fused2 = bn_reduce || scan_blocks ; fused3 = scan_bsums + bn_finalize
//   fused4 = scan_add + dinv ; fused5 = fill_edges || convert_inputs || pack_w
// Then: [gemm -> gather] x3 (MFMA gemm with LDS-staged A + packed-W frags;
// CSR gather with f32x2 packed accumulate).
// ---------------------------------------------------------------------------

typedef short bf16x8 __attribute__((ext_vector_type(8)));
typedef float f32x4 __attribute__((ext_vector_type(4)));
typedef float f32x2 __attribute__((ext_vector_type(2)));

#define BN_G 1024
#define SCAN_BLK 256
#define SCAN_ELEMS 1024

__device__ inline unsigned short f2bf(float f) {  // RNE
    unsigned int u = __builtin_bit_cast(unsigned int, f);
    u += 0x7fff + ((u >> 16) & 1);
    return (unsigned short)(u >> 16);
}
__device__ inline float bfl(unsigned int u) { return __builtin_bit_cast(float, u << 16); }
__device__ inline float bfh(unsigned int u) { return __builtin_bit_cast(float, u & 0xffff0000u); }
__device__ inline unsigned int pack2(float lo, float hi) {
    return ((unsigned int)f2bf(hi) << 16) | f2bf(lo);
}
__device__ inline f32x2 unp(unsigned int u) {
    return (f32x2){__builtin_bit_cast(float, u << 16),
                   __builtin_bit_cast(float, u & 0xffff0000u)};
}
__device__ inline void acc8v(f32x2* a, uint4 v) {   // vector adds -> v_pk_add_f32
    a[0] += unp(v.x); a[1] += unp(v.y); a[2] += unp(v.z); a[3] += unp(v.w);
}

__device__ __forceinline__ void gload_lds16(const void* g, void* l) {
    __builtin_amdgcn_global_load_lds(
        (const __attribute__((address_space(1))) unsigned int*)g,
        (__attribute__((address_space(3))) unsigned int*)l, 16, 0, 0);
}

// ---------------------------------------------------------------------------
// fused1: blocks [0,BN_G) = bn_stats partials ; [BN_G, BN_G+EB) = count_deg
// ---------------------------------------------------------------------------
__global__ __launch_bounds__(256) void fused1(const float4* __restrict__ x4,
                                              float* __restrict__ partials, int n,
                                              const int* __restrict__ ei,
                                              int* __restrict__ cnt,
                                              int* __restrict__ slot, int E) {
    __shared__ float4 lds[2][8][32];
    int bid = blockIdx.x, t = threadIdx.x;
    if (bid < BN_G) {
        int cg = t & 31;
        int rs = t >> 5;
        float4 s = make_float4(0.f, 0.f, 0.f, 0.f);
        float4 q = make_float4(0.f, 0.f, 0.f, 0.f);
        const float4 z4 = make_float4(0.f, 0.f, 0.f, 0.f);
        const int stride = BN_G * 32;
        for (int r0 = bid * 32 + rs * 4; r0 < n; r0 += stride) {
            float4 v0 = x4[(size_t)r0 * 32 + cg];
            float4 v1 = (r0 + 1 < n) ? x4[(size_t)(r0 + 1) * 32 + cg] : z4;
            float4 v2 = (r0 + 2 < n) ? x4[(size_t)(r0 + 2) * 32 + cg] : z4;
            float4 v3 = (r0 + 3 < n) ? x4[(size_t)(r0 + 3) * 32 + cg] : z4;
            s.x += v0.x + v1.x + v2.x + v3.x;
            s.y += v0.y + v1.y + v2.y + v3.y;
            s.z += v0.z + v1.z + v2.z + v3.z;
            s.w += v0.w + v1.w + v2.w + v3.w;
            q.x = fmaf(v0.x, v0.x, fmaf(v1.x, v1.x, fmaf(v2.x, v2.x, fmaf(v3.x, v3.x, q.x))));
            q.y = fmaf(v0.y, v0.y, fmaf(v1.y, v1.y, fmaf(v2.y, v2.y, fmaf(v3.y, v3.y, q.y))));
            q.z = fmaf(v0.z, v0.z, fmaf(v1.z, v1.z, fmaf(v2.z, v2.z, fmaf(v3.z, v3.z, q.z))));
            q.w = fmaf(v0.w, v0.w, fmaf(v1.w, v1.w, fmaf(v2.w, v2.w, fmaf(v3.w, v3.w, q.w))));
        }
        lds[0][rs][cg] = s;
        lds[1][rs][cg] = q;
        __syncthreads();
        if (t < 64) {
            int which = t >> 5;
            int c = t & 31;
            float4 a = lds[which][0][c];
#pragma unroll
            for (int i = 1; i < 8; i++) {
                float4 b = lds[which][i][c];
                a.x += b.x; a.y += b.y; a.z += b.z; a.w += b.w;
            }
            int base = which * 128 + c * 4;
            partials[(size_t)(base + 0) * BN_G + bid] = a.x;
            partials[(size_t)(base + 1) * BN_G + bid] = a.y;
            partials[(size_t)(base + 2) * BN_G + bid] = a.z;
            partials[(size_t)(base + 3) * BN_G + bid] = a.w;
        }
    } else {
        int e = (bid - BN_G) * 256 + t;
        if (e < E) slot[e] = atomicAdd(&cnt[ei[E + e]], 1);
    }
}

// ---------------------------------------------------------------------------
// fused2: blocks [0,256) = bn_reduce ; [256, 256+nb) = scan_blocks
// ---------------------------------------------------------------------------
__global__ __launch_bounds__(256) void fused2(const float4* __restrict__ partials4,
                                              float* __restrict__ stats,
                                              const int* __restrict__ cnt,
                                              int* __restrict__ row_ptr,
                                              int* __restrict__ bsums, int n) {
    __shared__ float red[256];
    __shared__ int lds[SCAN_BLK];
    int t = threadIdx.x;
    if (blockIdx.x < 256) {
        int c = blockIdx.x;
        float4 v = partials4[(size_t)c * (BN_G / 4) + t];
        red[t] = v.x + v.y + v.z + v.w;
        __syncthreads();
        for (int off = 128; off > 0; off >>= 1) {
            if (t < off) red[t] += red[t + off];
            __syncthreads();
        }
        if (t == 0) stats[c] = red[0];
    } else {
        int blk = blockIdx.x - 256;
        int base = blk * SCAN_ELEMS;
        int v[4];
        int s = 0;
#pragma unroll
        for (int j = 0; j < 4; j++) {
            int i = base + t * 4 + j;
            v[j] = s;
            s += (i < n) ? cnt[i] : 0;
        }
        lds[t] = s;
        __syncthreads();
        for (int off = 1; off < SCAN_BLK; off <<= 1) {
            int val = (t >= off) ? lds[t - off] : 0;
            __syncthreads();
            lds[t] += val;
            __syncthreads();
        }
        int excl = (t == 0) ? 0 : lds[t - 1];
#pragma unroll
        for (int j = 0; j < 4; j++) {
            int i = base + t * 4 + j;
            if (i < n) row_ptr[i] = excl + v[j];
        }
        if (t == SCAN_BLK - 1) bsums[blk] = lds[t];
    }
}

// ---------------------------------------------------------------------------
// fused3 (1 block): t==0 serial-scans bsums ; t in [128,256) bn_finalize
// ---------------------------------------------------------------------------
__global__ void fused3(int* __restrict__ bsums, int nb,
                       const float* __restrict__ stats,
                       const float* __restrict__ gamma, const float* __restrict__ beta,
                       float* __restrict__ scale, float* __restrict__ shift, float invN) {
    int t = threadIdx.x;
    if (t == 0) {
        int acc = 0;
        for (int i = 0; i < nb; i++) { int c = bsums[i]; bsums[i] = acc; acc += c; }
    } else if (t >= 128 && t < 256) {
        int c = t - 128;
        float mu = stats[c] * invN;
        float var = stats[128 + c] * invN - mu * mu;
        float sc = gamma[c] / sqrtf(var + 1e-5f);
        scale[c] = sc;
        shift[c] = beta[c] - mu * sc;
    }
}

// ---------------------------------------------------------------------------
// fused4: scan_add + dinv in one pass over nodes
// ---------------------------------------------------------------------------
__global__ void fused4(int* __restrict__ row_ptr, const int* __restrict__ bsums,
                       const int* __restrict__ cnt, float* __restrict__ dinv,
                       int n, int E) {
    int i = blockIdx.x * blockDim.x + threadIdx.x;
    if (i < n) {
        row_ptr[i] += bsums[i / SCAN_ELEMS];
        dinv[i] = rsqrtf((float)cnt[i] + 1.0f);
    }
    if (i == 0) row_ptr[n] = E;
}

// ---------------------------------------------------------------------------
// pack W (fp32 [K][C], col slice at colOff) into MFMA fragment layout.
// ---------------------------------------------------------------------------
__device__ inline void pack_body(int i, const float* __restrict__ W,
                                 unsigned short* __restrict__ Wp,
                                 int K, int C, int colOff) {
    if (i >= K * C) return;
    int k = i / C, c = i % C;
    int gc = c + colOff;
    int s = k >> 7, kc = (k >> 5) & 3, lhi = (k >> 3) & 3, j = k & 7;
    int wc = gc >> 6, n = (gc >> 4) & 3, l15 = gc & 15;
    int lane = lhi * 16 + l15;
    size_t dst = ((size_t)((s * 2 + wc) * 4 + kc) * 4 + n) * 512 + lane * 8 + j;
    Wp[dst] = f2bf(W[i]);
}

// ---------------------------------------------------------------------------
// fused5: fill_edges || convert_inputs || pack_w x4
// ---------------------------------------------------------------------------
__global__ __launch_bounds__(256) void fused5(
    const int* __restrict__ ei, const int* __restrict__ row_ptr,
    const int* __restrict__ slot, int* __restrict__ edge_src, int E, int EB,
    const float4* __restrict__ x4, const float4* __restrict__ n4,
    const float* __restrict__ scale, const float* __restrict__ shift,
    ushort4* __restrict__ xb, ushort4* __restrict__ nb4, int total4, int CB,
    const float* __restrict__ W1, unsigned short* __restrict__ Wp1,
    const float* __restrict__ W2, unsigned short* __restrict__ Wp2,
    const float* __restrict__ Wm, const float* __restrict__ Ws,
    unsigned short* __restrict__ Wpc)
{
    int bid = blockIdx.x, t = threadIdx.x;
    if (bid < EB) {
        int e = bid * 256 + t;
        if (e < E) {
            int s = ei[e], d = ei[E + e];
            edge_src[row_ptr[d] + slot[e]] = s;
        }
        return;
    }
    bid -= EB;
    if (bid < CB) {
        int i = bid * 256 + t;
        if (i < total4) {
            int c4 = (i & 31) << 2;
            float4 sc = *reinterpret_cast<const float4*>(scale + c4);
            float4 sh = *reinterpret_cast<const float4*>(shift + c4);
            float4 v = x4[i];
            ushort4 o;
            o.x = f2bf(fmaf(v.x, sc.x, sh.x));
            o.y = f2bf(fmaf(v.y, sc.y, sh.y));
            o.z = f2bf(fmaf(v.z, sc.z, sh.z));
            o.w = f2bf(fmaf(v.w, sc.w, sh.w));
            xb[i] = o;
            float4 w = n4[i];
            ushort4 p;
            p.x = f2bf(w.x); p.y = f2bf(w.y); p.z = f2bf(w.z); p.w = f2bf(w.w);
            nb4[i] = p;
        }
        return;
    }
    bid -= CB;
    if (bid < 64)  { pack_body(bid * 256 + t, W1, Wp1, 128, 128, 0); return; }
    bid -= 64;
    if (bid < 192) { pack_body(bid * 256 + t, W2, Wp2, 384, 128, 0); return; }
    bid -= 192;
    if (bid < 64)  { pack_body(bid * 256 + t, Wm, Wpc, 256, 64, 0); return; }
    bid -= 64;
    pack_body(bid * 256 + t, Ws, Wpc, 256, 64, 64);
}

// ---------------------------------------------------------------------------
// MFMA GEMM: hs[MP x 128] = (sum_s A_s[MP x 128] @ W[s*128:, :]) * dinv[row]
// ---------------------------------------------------------------------------
template <int NSRC>
__global__ __launch_bounds__(256, 4) void gemm_mfma(
    const unsigned short* __restrict__ A0, const unsigned short* __restrict__ A1,
    const unsigned short* __restrict__ A2,
    const unsigned short* __restrict__ Wpk,  // packed fragments
    const float* __restrict__ dinv, unsigned short* __restrict__ out)
{
    constexpr int NBUF = (NSRC > 1) ? 2 : 1;
    __shared__ unsigned char ldsA[NBUF][64 * 256];   // [rows][128k * 2B]

    const int lane = threadIdx.x & 63;
    const int wid  = threadIdx.x >> 6;
    const int wr   = wid >> 1, wc = wid & 1;
    const int l15  = lane & 15, lhi = lane >> 4;
    const int c0   = wc * 64;
    const long rowblk = (long)blockIdx.x * 64;
    const int rl0 = wr * 32 + l15;
    const int rl1 = rl0 + 16;
    const int rsw = rl0 & 7;

    const unsigned short* __restrict__ srcs[3] = {A0, A1, A2};
    auto stage = [&](int s, int b) {
#pragma unroll
        for (int i = 0; i < 4; i++) {
            int G = (wid * 4 + i) * 64 + lane;
            int r = G >> 4, g = G & 15;
            const unsigned short* src = srcs[s] + (rowblk + r) * 128 + (g ^ (r & 7)) * 8;
            gload_lds16(src, &ldsA[b][G * 16]);
        }
    };

    f32x4 acc[2][4];
#pragma unroll
    for (int g = 0; g < 2; g++)
#pragma unroll
        for (int n = 0; n < 4; n++)
            acc[g][n] = (f32x4){0.f, 0.f, 0.f, 0.f};

    stage(0, 0);

#pragma unroll
    for (int s = 0; s < NSRC; s++) {
        const unsigned short* wbase = Wpk + ((size_t)(s * 2 + wc) * 16) * 512 + lane * 8;
        bf16x8 w[4][4];
#pragma unroll
        for (int kc = 0; kc < 4; kc++)
#pragma unroll
            for (int n = 0; n < 4; n++)
                w[kc][n] = *reinterpret_cast<const bf16x8*>(wbase + (kc * 4 + n) * 512);

        __syncthreads();                         // stage(s) + W(s) complete
        if (s + 1 < NSRC) stage(s + 1, (s + 1) % NBUF);
        const unsigned char* bufp = ldsA[s % NBUF];

#pragma unroll
        for (int kc = 0; kc < 4; kc++) {
            int g0 = kc * 4 + lhi;
            bf16x8 a0 = *reinterpret_cast<const bf16x8*>(bufp + rl0 * 256 + (g0 ^ rsw) * 16);
            bf16x8 a1 = *reinterpret_cast<const bf16x8*>(bufp + rl1 * 256 + (g0 ^ rsw) * 16);
#pragma unroll
            for (int n = 0; n < 4; n++) {
                acc[0][n] = __builtin_amdgcn_mfma_f32_16x16x32_bf16(w[kc][n], a0, acc[0][n], 0, 0, 0);
                acc[1][n] = __builtin_amdgcn_mfma_f32_16x16x32_bf16(w[kc][n], a1, acc[1][n], 0, 0, 0);
            }
        }
    }

#pragma unroll
    for (int g = 0; g < 2; g++) {
        long row = rowblk + (g ? rl1 : rl0);
        float dv = dinv[row];
        unsigned short* op = out + row * 128 + c0 + lhi * 4;
#pragma unroll
        for (int n = 0; n < 4; n++) {
            f32x4 v = acc[g][n];
            ushort4 pk;
            pk.x = f2bf(v[0] * dv);
            pk.y = f2bf(v[1] * dv);
            pk.z = f2bf(v[2] * dv);
            pk.w = f2bf(v[3] * dv);
            *reinterpret_cast<ushort4*>(op + n * 16) = pk;
        }
    }
}

// ---------------------------------------------------------------------------
// CSR gather: one wave per node; 16 lanes x uint4 cover one 256B row;
// 4 sub-groups stride the edge list; f32x2 packed accumulate (v_pk_add_f32).
// ---------------------------------------------------------------------------
template <bool RELU>
__global__ void gather16(const uint4* __restrict__ hs4, const float* __restrict__ dinv,
                         const int* __restrict__ row_ptr, const int* __restrict__ edge_src,
                         const float* __restrict__ bias, uint4* __restrict__ out4, int n) {
    int node = blockIdx.x * 4 + (threadIdx.x >> 6);
    if (node >= n) return;
    int lane = threadIdx.x & 63;
    int cl = lane & 15, sub = lane >> 4;
    int beg = row_ptr[node], end = row_ptr[node + 1];
    f32x2 a0[4] = {(f32x2){0.f,0.f}, (f32x2){0.f,0.f}, (f32x2){0.f,0.f}, (f32x2){0.f,0.f}};
    f32x2 a1[4] = {(f32x2){0.f,0.f}, (f32x2){0.f,0.f}, (f32x2){0.f,0.f}, (f32x2){0.f,0.f}};
    if (sub == 0) acc8v(a0, hs4[(size_t)node * 16 + cl]);   // self-loop
    int e = beg + sub;
    for (; e + 4 < end; e += 8) {
        uint4 v0 = hs4[(size_t)edge_src[e] * 16 + cl];
        uint4 v1 = hs4[(size_t)edge_src[e + 4] * 16 + cl];
        acc8v(a0, v0);
        acc8v(a1, v1);
    }
    if (e < end) acc8v(a0, hs4[(size_t)edge_src[e] * 16 + cl]);
#pragma unroll
    for (int i = 0; i < 4; i++) a0[i] += a1[i];
#pragma unroll
    for (int i = 0; i < 4; i++) {
        a0[i].x += __shfl_xor(a0[i].x, 16);
        a0[i].y += __shfl_xor(a0[i].y, 16);
        a0[i].x += __shfl_xor(a0[i].x, 32);
        a0[i].y += __shfl_xor(a0[i].y, 32);
    }
    if (sub == 0) {
        float dv = dinv[node];
        float4 b0 = *reinterpret_cast<const float4*>(bias + cl * 8);
        float4 b1 = *reinterpret_cast<const float4*>(bias + cl * 8 + 4);
        float r0 = fmaf(a0[0].x, dv, b0.x), r1 = fmaf(a0[0].y, dv, b0.y);
        float r2 = fmaf(a0[1].x, dv, b0.z), r3 = fmaf(a0[1].y, dv, b0.w);
        float r4 = fmaf(a0[2].x, dv, b1.x), r5 = fmaf(a0[2].y, dv, b1.y);
        float r6 = fmaf(a0[3].x, dv, b1.z), r7 = fmaf(a0[3].y, dv, b1.w);
        if (RELU) {
            r0 = fmaxf(r0, 0.f); r1 = fmaxf(r1, 0.f); r2 = fmaxf(r2, 0.f); r3 = fmaxf(r3, 0.f);
            r4 = fmaxf(r4, 0.f); r5 = fmaxf(r5, 0.f); r6 = fmaxf(r6, 0.f); r7 = fmaxf(r7, 0.f);
        }
        uint4 o;
        o.x = pack2(r0, r1); o.y = pack2(r2, r3);
        o.z = pack2(r4, r5); o.w = pack2(r6, r7);
        out4[(size_t)node * 16 + cl] = o;
    }
}

// final: t rows = [tm(64) | ts(64)] bf16 -> zm, zs fp32
__global__ void gather_dual(const uint4* __restrict__ hs4, const float* __restrict__ dinv,
                            const int* __restrict__ row_ptr, const int* __restrict__ edge_src,
                            const float* __restrict__ bm, const float* __restrict__ bs,
                            float* __restrict__ zm, float* __restrict__ zs, int n) {
    int node = blockIdx.x * 4 + (threadIdx.x >> 6);
    if (node >= n) return;
    int lane = threadIdx.x & 63;
    int cl = lane & 15, sub = lane >> 4;
    int beg = row_ptr[node], end = row_ptr[node + 1];
    f32x2 a0[4] = {(f32x2){0.f,0.f}, (f32x2){0.f,0.f}, (f32x2){0.f,0.f}, (f32x2){0.f,0.f}};
    f32x2 a1[4] = {(f32x2){0.f,0.f}, (f32x2){0.f,0.f}, (f32x2){0.f,0.f}, (f32x2){0.f,0.f}};
    if (sub == 0) acc8v(a0, hs4[(size_t)node * 16 + cl]);
    int e = beg + sub;
    for (; e + 4 < end; e += 8) {
        uint4 v0 = hs4[(size_t)edge_src[e] * 16 + cl];
        uint4 v1 = hs4[(size_t)edge_src[e + 4] * 16 + cl];
        acc8v(a0, v0);
        acc8v(a1, v1);
    }
    if (e < end) acc8v(a0, hs4[(size_t)edge_src[e] * 16 + cl]);
#pragma unroll
    for (int i = 0; i < 4; i++) a0[i] += a1[i];
#pragma unroll
    for (int i = 0; i < 4; i++) {
        a0[i].x += __shfl_xor(a0[i].x, 16);
        a0[i].y += __shfl_xor(a0[i].y, 16);
        a0[i].x += __shfl_xor(a0[i].x, 32);
        a0[i].y += __shfl_xor(a0[i].y, 32);
    }
    if (sub == 0) {
        float dv = dinv[node];
        const float* bp = (cl < 8) ? (bm + cl * 8) : (bs + (cl - 8) * 8);
        float* zp = (cl < 8) ? (zm + (size_t)node * 64 + cl * 8)
                             : (zs + (size_t)node * 64 + (cl - 8) * 8);
        float4 b0 = *reinterpret_cast<const float4*>(bp);
        float4 b1 = *reinterpret_cast<const float4*>(bp + 4);
        float4 o0 = make_float4(fmaf(a0[0].x, dv, b0.x), fmaf(a0[0].y, dv, b0.y),
                                fmaf(a0[1].x, dv, b0.z), fmaf(a0[1].y, dv, b0.w));
        float4 o1 = make_float4(fmaf(a0[2].x, dv, b1.x), fmaf(a0[2].y, dv, b1.y),
                                fmaf(a0[3].x, dv, b1.z), fmaf(a0[3].y, dv, b1.w));
        *reinterpret_cast<float4*>(zp) = o0;
        *reinterpret_cast<float4*>(zp + 4) = o1;
    }
}

// ---------------------------------------------------------------------------

extern "C" void kernel_launch(void* const* d_in, const int* in_sizes, int n_in,
                              void* d_out, int out_size, void* d_ws, size_t ws_size,
                              hipStream_t stream) {
    const float* x     = (const float*)d_in[0];
    const float* noise = (const float*)d_in[1];
    const int*   ei    = (const int*)d_in[2];
    const float* gamma = (const float*)d_in[3];
    const float* beta  = (const float*)d_in[4];
    const float* W1    = (const float*)d_in[5];
    const float* b1    = (const float*)d_in[6];
    const float* W2    = (const float*)d_in[7];
    const float* b2    = (const float*)d_in[8];
    const float* Wm    = (const float*)d_in[9];
    const float* bm    = (const float*)d_in[10];
    const float* Ws    = (const float*)d_in[11];
    const float* bs    = (const float*)d_in[12];

    const int N  = in_sizes[0] / 128;
    const int E  = in_sizes[2] / 2;
    const int NPAD = (N + 127) & ~127;
    const int nb = (N + SCAN_ELEMS - 1) / SCAN_ELEMS;
    const int EB = (E + 255) / 256;
    const int CB = (N * 32 + 255) / 256;

    auto align256 = [](size_t b) { return (b + 255) & ~(size_t)255; };
    char* p = (char*)d_ws;
    int* cnt      = (int*)p;  p += align256((size_t)N * 4);
    int* row_ptr  = (int*)p;  p += align256((size_t)(N + 1) * 4);
    int* edge_src = (int*)p;  p += align256((size_t)E * 4);
    int* slot     = (int*)p;  p += align256((size_t)E * 4);
    int* bsums    = (int*)p;  p += align256((size_t)nb * 4);
    float* dinv   = (float*)p; p += align256((size_t)NPAD * 4);
    float* stats  = (float*)p; p += align256(512 * 4);
    float* bnpart = (float*)p; p += align256((size_t)256 * BN_G * 4);
    unsigned short* Wp1 = (unsigned short*)p; p += align256(128 * 128 * 2);
    unsigned short* Wp2 = (unsigned short*)p; p += align256(128 * 384 * 2);
    unsigned short* Wpc = (unsigned short*)p; p += align256(128 * 256 * 2);
    unsigned short* xb16 = (unsigned short*)p; p += align256((size_t)NPAD * 128 * 2);
    unsigned short* n16  = (unsigned short*)p; p += align256((size_t)NPAD * 128 * 2);
    unsigned short* h16  = (unsigned short*)p; p += align256((size_t)NPAD * 128 * 2);

    float* scale = stats + 256;
    float* shift = stats + 384;

    float* dout = (float*)d_out;                       // N*128 fp32
    unsigned short* hs12 = (unsigned short*)d_out;     // conv1/2 hs scratch
    unsigned short* hs3  = n16;                        // noise dead after conv2
    float* zm = dout;                                  // [N*64]
    float* zs = dout + (size_t)N * 64;                 // [N*64]

    const int gblocks = NPAD / 64;
    const int nblocks4 = (N + 3) / 4;

    // --- fused setup DAG ---
    hipMemsetAsync(cnt, 0, (size_t)N * 4, stream);
    fused1<<<BN_G + EB, 256, 0, stream>>>((const float4*)x, bnpart, N, ei, cnt, slot, E);
    fused2<<<256 + nb, 256, 0, stream>>>((const float4*)bnpart, stats, cnt, row_ptr, bsums, N);
    fused3<<<1, 256, 0, stream>>>(bsums, nb, stats, gamma, beta, scale, shift, 1.0f / (float)N);
    fused4<<<(N + 255) / 256, 256, 0, stream>>>(row_ptr, bsums, cnt, dinv, N, E);
    fused5<<<EB + CB + 384, 256, 0, stream>>>(
        ei, row_ptr, slot, edge_src, E, EB,
        (const float4*)x, (const float4*)noise, scale, shift,
        (ushort4*)xb16, (ushort4*)n16, N * 32, CB,
        W1, Wp1, W2, Wp2, Wm, Ws, Wpc);

    // conv1
    gemm_mfma<1><<<gblocks, 256, 0, stream>>>(xb16, nullptr, nullptr, Wp1, dinv, hs12);
    gather16<true><<<nblocks4, 256, 0, stream>>>((const uint4*)hs12, dinv, row_ptr,
                                                 edge_src, b1, (uint4*)h16, N);
    // conv2
    gemm_mfma<3><<<gblocks, 256, 0, stream>>>(xb16, n16, h16, Wp2, dinv, hs12);
    gather16<true><<<nblocks4, 256, 0, stream>>>((const uint4*)hs12, dinv, row_ptr,
                                                 edge_src, b2, (uint4*)h16, N);
    // mean/logstd fused
    gemm_mfma<2><<<gblocks, 256, 0, stream>>>(xb16, h16, nullptr, Wpc, dinv, hs3);
    gather_dual<<<nblocks4, 256, 0, stream>>>((const uint4*)hs3, dinv, row_ptr,
                                              edge_src, bm, bs, zm, zs, N);
}